// Round 4
// baseline (30976.669 us; speedup 1.0000x reference)
//
#include <hip/hip_runtime.h>
#include <math.h>

// ---------------------------------------------------------------------------
// CurvePredictor R11: 16-way hidden-column split, register-resident weights.
// R7-R10 post-mortem: the 6.5ms floor was the per-CU L2 weight re-stream
// (1.58 MB/step/CU, ~62 GB/s/CU effective); occupancy fixes at 1024 thr
// never materialized (compiler pinned 64 VGPR, spill/refetch thrashed L2
// to 14.3 GB HBM). R11 removes the stream entirely:
//  - 256 blocks x 512 thr on 256 CUs: 16 groups (128 batch rows each) x
//    16 members (16 hidden cols each, = image slice m).
//  - Each wave = (gate, row-half); holds its Whh0/Wih1/Whh1 B-frags in
//    REGISTERS (96 VGPR), loaded once. Weights never re-read.
//  - Per step: phase A (gates0=xp0+h0@Whh0 -> h0'), phase B (gates1=bs1+
//    h0'@Wih1+h1@Whh1 -> h1'), phase C (d=gelu(h1'@W3), out=d@W4, 8 rows).
//    h chunks exchanged via global (L2, same-XCD groups via bid%8), peers
//    synced with agent-scope atomic counters (2 spins/step, step-indexed).
//  - LDS: 32KB f32 gate staging (cross-wave i/f/g/o gather) + pad to 84KB
//    to force 1 block/CU. Grid 256 <= 256 CUs => all blocks co-resident.
// Hazard audit: every buffer overwrite at step t is ordered behind a
// counter that the previous readers of that buffer arrived at (cnt0[t]
// covers h0 parity reuse, cnt1[t] covers h1; phase C reads guarded by
// cnt1[t]; pstg/gstg reuse separated by >=2 __syncthreads).
// ---------------------------------------------------------------------------

typedef short s8v __attribute__((ext_vector_type(8)));   // 8 x bf16
typedef float f4v __attribute__((ext_vector_type(4)));   // 4 x f32

// ---- ws layout (units: shorts) ----
#define IMG_SHORTS   1084416                 // swizzled weight image (padded)
#define ENC_OFF      IMG_SHORTS              // encg [16 grp][144 rows][256] bf16
#define ENC_SHORTS   (16*144*256)
#define H0_OFF       (ENC_OFF + ENC_SHORTS)  // h0g [2 parity][16][144][256] bf16
#define H_SHORTS     (2*16*144*256)
#define H1_OFF       (H0_OFF + H_SHORTS)
#define CNT_OFF      (H1_OFF + H_SHORTS)     // u32 cnt[2][16][264]

__device__ __forceinline__ f4v mfma16(s8v a, s8v b, f4v c){
  return __builtin_amdgcn_mfma_f32_16x16x32_bf16(a, b, c, 0, 0, 0);
}
__device__ __forceinline__ short f2bf(float f){
  unsigned u = __float_as_uint(f);
  u = u + 0x7FFFu + ((u >> 16) & 1u);
  return (short)(u >> 16);
}
__device__ __forceinline__ float wred(float v){
  #pragma unroll
  for (int o = 32; o; o >>= 1) v += __shfl_xor(v, o);
  return v;
}
__device__ __forceinline__ float sigm(float x){ return 1.0f / (1.0f + __expf(-x)); }
__device__ __forceinline__ float tnh(float x){
  x = fminf(15.0f, fmaxf(-15.0f, x));
  float e = __expf(2.0f * x);
  return (e - 1.0f) / (e + 1.0f);
}
__device__ __forceinline__ float gelu(float v){
  return 0.5f * v * (1.0f + erff(v * 0.70710678118654752440f));
}

// ws image layout (shorts), same swizzle as R5-R10:
// main matrices (1024x256): elem = s*16384 + g*4096 + kk*512 + lane*8 + j
//   [0,262144) Wih0 [262144,524288) Whh0 [524288,786432) Wih1 [786432,1048576) Whh1
// W3 [128][256]: 1048576 + s2*4096 + kk*512 + lane*8
// W4 padded:     1081344 (unused by R11 main kernel; kept for prep parity)
__global__ void prep_kernel(
    const float* __restrict__ Wih0, const float* __restrict__ Whh0,
    const float* __restrict__ Wih1, const float* __restrict__ Whh1,
    const float* __restrict__ W3,   const float* __restrict__ W4,
    short* __restrict__ wsb)
{
  const int i = blockIdx.x * 256 + threadIdx.x;
  if (i >= 1083392) return;
  float v;
  if (i < 1048576){
    const int seg = i >> 18;
    const int r   = i & 262143;
    const int s   = r >> 14;
    const int g   = (r >> 12) & 3;
    const int kk  = (r >> 9) & 7;
    const int q   = (r >> 7) & 3;
    const int m16 = (r >> 3) & 15;
    const int j   = r & 7;
    const int hid = s * 16 + m16;
    const int k   = kk * 32 + q * 8 + j;
    const float* mt = (seg == 0) ? Wih0 : (seg == 1) ? Whh0 : (seg == 2) ? Wih1 : Whh1;
    v = mt[(g * 256 + hid) * 256 + k];
  } else if (i < 1081344){
    const int r   = i - 1048576;
    const int s2  = r >> 12;
    const int kk  = (r >> 9) & 7;
    const int q   = (r >> 7) & 3;
    const int m16 = (r >> 3) & 15;
    const int j   = r & 7;
    v = W3[(s2 * 16 + m16) * 256 + kk * 32 + q * 8 + j];
  } else {
    const int r   = i - 1081344;
    const int kk  = (r >> 9) & 3;
    const int q   = (r >> 7) & 3;
    const int m16 = (r >> 3) & 15;
    const int j   = r & 7;
    const int k   = kk * 32 + q * 8 + j;
    v = (m16 < 2) ? W4[m16 * 128 + k] : 0.0f;
  }
  wsb[i] = f2bf(v);
}

// 64-row (4 rowtile) x 16-col gate slice gemm, K=256, B in registers.
// Two 16-load SSA batches (proven R7 latency-amortization pattern).
__device__ __forceinline__ void gemm64(
    const short* __restrict__ hA, const s8v (&B)[8], int m16, int q, f4v (&acc)[4])
{
  #pragma unroll
  for (int hf = 0; hf < 2; hf++){
    s8v A[16];
    #pragma unroll
    for (int f = 0; f < 16; f++){
      const int rt = hf * 2 + (f >> 3);
      const int kk = f & 7;
      A[f] = *(const s8v*)(hA + (rt * 16 + m16) * 256 + kk * 32 + q * 8);
    }
    #pragma unroll
    for (int f = 0; f < 16; f++){
      const int rt = hf * 2 + (f >> 3);
      acc[rt] = mfma16(A[f], B[f & 7], acc[rt]);
    }
  }
}

// 16-member group barrier: release-add, relaxed poll, acquire, block barrier.
__device__ __forceinline__ void group_barrier(unsigned* c, int tid){
  __threadfence();                 // publish this block's global writes
  __syncthreads();                 // all waves' writes issued before arrive
  if (tid == 0){
    __hip_atomic_fetch_add(c, 1u, __ATOMIC_RELEASE, __HIP_MEMORY_SCOPE_AGENT);
    unsigned it = 0;
    while (__hip_atomic_load(c, __ATOMIC_RELAXED, __HIP_MEMORY_SCOPE_AGENT) < 16u){
      __builtin_amdgcn_s_sleep(2);
      if (++it > (1u << 26)) break;          // failsafe: finite on deadlock
    }
    (void)__hip_atomic_load(c, __ATOMIC_ACQUIRE, __HIP_MEMORY_SCOPE_AGENT); // L1 inv
  }
  __syncthreads();
}

__global__ __launch_bounds__(512) void curve_rec(
    const float* __restrict__ x,
    const float* __restrict__ W1, const float* __restrict__ b1,
    const float* __restrict__ g1, const float* __restrict__ be1,
    const float* __restrict__ W2, const float* __restrict__ b2,
    const float* __restrict__ g2, const float* __restrict__ be2,
    const float* __restrict__ bih0, const float* __restrict__ bhh0,
    const float* __restrict__ bih1, const float* __restrict__ bhh1,
    const float* __restrict__ b3, const float* __restrict__ b4,
    const float* __restrict__ W4,
    short* __restrict__ wsb,
    float* __restrict__ out)
{
  const int tid  = threadIdx.x;
  const int v    = tid >> 6;          // wave 0..7
  const int lane = tid & 63;
  const int q    = lane >> 4;
  const int m16  = lane & 15;
  const int bid  = blockIdx.x;
  const int g    = (bid & 7) * 2 + (bid >> 7);   // group 0..15 (same-XCD members)
  const int m    = (bid >> 3) & 15;              // member 0..15 = hid slice
  const int gate = v & 3;                        // wave's gate (i,f,g,o)
  const int rh   = v >> 2;                       // wave's row-half (64 rows)
  const int grow0 = g * 128;                     // group's first batch row

  const short* img  = wsb;
  short*       encg = wsb + ENC_OFF;
  short*       h0g  = wsb + H0_OFF;
  short*       h1g  = wsb + H1_OFF;
  unsigned*    cntb = (unsigned*)(wsb + CNT_OFF);
  unsigned*    cnt0 = cntb + g * 264;            // [t]=phaseA arrivals, [256]=enc
  unsigned*    cnt1 = cntb + 16 * 264 + g * 264; // [t]=phaseB arrivals

  __shared__ __align__(16) char smem[84224];     // >80KiB => 1 block/CU
  float* gstg = (float*)smem;                    // [4 gates][128 rows][16] f32
  float* pstg = (float*)(smem + 32768);          // [8 waves][8 rows][2] f32

  // ---- persistent register-resident B fragments (loaded once) ----
  s8v Bh0[8], Bi1[8], Bh1[8];
  #pragma unroll
  for (int kk = 0; kk < 8; kk++){
    const int off = m * 16384 + gate * 4096 + kk * 512 + (lane << 3);
    Bh0[kk] = *(const s8v*)(img + 262144 + off);
    Bi1[kk] = *(const s8v*)(img + 524288 + off);
    Bh1[kk] = *(const s8v*)(img + 786432 + off);
  }
  const float w40 = W4[v * 16 + m16];            // phase C: dct = v
  const float w41 = W4[128 + v * 16 + m16];
  const float b3c = b3[v * 16 + m16];
  const float b4v = b4[lane & 1];

  // ---- encoder: wave v computes batch row m*8+v of this group ----
  {
    const int row_l = m * 8 + v;
    const int r = grow0 + row_l;
    float xv[5];
    #pragma unroll
    for (int k = 0; k < 5; k++) xv[k] = x[r * 5 + k];
    float a0 = b1[lane], a1 = b1[lane + 64];
    #pragma unroll
    for (int k = 0; k < 5; k++){
      a0 += xv[k] * W1[lane * 5 + k];
      a1 += xv[k] * W1[(lane + 64) * 5 + k];
    }
    a0 = gelu(a0); a1 = gelu(a1);
    float mean = wred(a0 + a1) * (1.0f / 128.0f);
    float d0 = a0 - mean, d1 = a1 - mean;
    float inv = rsqrtf(wred(d0 * d0 + d1 * d1) * (1.0f / 128.0f) + 1e-5f);
    float y0 = d0 * inv * g1[lane]      + be1[lane];
    float y1 = d1 * inv * g1[lane + 64] + be1[lane + 64];

    float acc2[4];
    #pragma unroll
    for (int uu = 0; uu < 4; uu++) acc2[uu] = b2[lane + 64 * uu];
    for (int k = 0; k < 64; k++){
      float v0 = __shfl(y0, k);
      float v1 = __shfl(y1, k);
      #pragma unroll
      for (int uu = 0; uu < 4; uu++){
        const float* wr = W2 + (lane + 64 * uu) * 128;
        acc2[uu] += v0 * wr[k] + v1 * wr[k + 64];
      }
    }
    #pragma unroll
    for (int uu = 0; uu < 4; uu++) acc2[uu] = gelu(acc2[uu]);
    float s = acc2[0] + acc2[1] + acc2[2] + acc2[3];
    mean = wred(s) * (1.0f / 256.0f);
    float vv = 0.0f;
    #pragma unroll
    for (int uu = 0; uu < 4; uu++){ float d = acc2[uu] - mean; vv += d * d; }
    inv = rsqrtf(wred(vv) * (1.0f / 256.0f) + 1e-5f);
    #pragma unroll
    for (int uu = 0; uu < 4; uu++){
      int c = lane + 64 * uu;
      float e = (acc2[uu] - mean) * inv * g2[c] + be2[c];
      encg[(g * 144 + row_l) * 256 + c] = f2bf(e);
    }
  }
  group_barrier(cnt0 + 256, tid);                // enc visible group-wide

  // ---- xp0 = enc @ Wih0_slice^T + (bih0+bhh0), register-resident ----
  f4v xp[4];
  {
    s8v Wi0[8];
    #pragma unroll
    for (int kk = 0; kk < 8; kk++)
      Wi0[kk] = *(const s8v*)(img + m * 16384 + gate * 4096 + kk * 512 + (lane << 3));
    const int n = gate * 256 + m * 16 + m16;
    const float bi = bih0[n] + bhh0[n];
    #pragma unroll
    for (int rt = 0; rt < 4; rt++){ f4v tv = {bi, bi, bi, bi}; xp[rt] = tv; }
    gemm64(encg + (g * 144 + rh * 64) * 256, Wi0, m16, q, xp);
  }
  const int n1 = gate * 256 + m * 16 + m16;
  const float bs1 = bih1[n1] + bhh1[n1];
  float c0[4] = {0.f, 0.f, 0.f, 0.f}, c1[4] = {0.f, 0.f, 0.f, 0.f};

  // --------------------------- recurrence over T ---------------------------
  #pragma unroll 1
  for (int t = 0; t < 256; t++){
    const int pin = t & 1, pout = pin ^ 1;

    // ---- phase A: gates0 = xp0 + h0_old @ Whh0_g -> gstg ----
    {
      f4v acc[4];
      #pragma unroll
      for (int rt = 0; rt < 4; rt++) acc[rt] = xp[rt];
      gemm64(h0g + ((pin * 16 + g) * 144 + rh * 64) * 256, Bh0, m16, q, acc);
      #pragma unroll
      for (int rt = 0; rt < 4; rt++)
        #pragma unroll
        for (int r = 0; r < 4; r++)
          gstg[(gate * 128 + rh * 64 + rt * 16 + q * 4 + r) * 16 + m16] = acc[rt][r];
    }
    __syncthreads();
    // pointwise: wave v updates rows v*16..+15, hid col m*16+m16
    #pragma unroll
    for (int r = 0; r < 4; r++){
      const int row = v * 16 + q * 4 + r;
      const float ii = sigm(gstg[(0 * 128 + row) * 16 + m16]);
      const float ff = sigm(gstg[(1 * 128 + row) * 16 + m16]);
      const float gg = tnh (gstg[(2 * 128 + row) * 16 + m16]);
      const float oo = sigm(gstg[(3 * 128 + row) * 16 + m16]);
      c0[r] = ff * c0[r] + ii * gg;
      h0g[((pout * 16 + g) * 144 + row) * 256 + m * 16 + m16] = f2bf(oo * tnh(c0[r]));
    }
    group_barrier(cnt0 + t, tid);                // h0_new visible group-wide

    // ---- phase B: gates1 = bs1 + h0_new@Wih1_g + h1_old@Whh1_g -> gstg ----
    {
      f4v acc[4];
      #pragma unroll
      for (int rt = 0; rt < 4; rt++){ f4v tv = {bs1, bs1, bs1, bs1}; acc[rt] = tv; }
      gemm64(h0g + ((pout * 16 + g) * 144 + rh * 64) * 256, Bi1, m16, q, acc);
      gemm64(h1g + ((pin  * 16 + g) * 144 + rh * 64) * 256, Bh1, m16, q, acc);
      #pragma unroll
      for (int rt = 0; rt < 4; rt++)
        #pragma unroll
        for (int r = 0; r < 4; r++)
          gstg[(gate * 128 + rh * 64 + rt * 16 + q * 4 + r) * 16 + m16] = acc[rt][r];
    }
    __syncthreads();
    #pragma unroll
    for (int r = 0; r < 4; r++){
      const int row = v * 16 + q * 4 + r;
      const float ii = sigm(gstg[(0 * 128 + row) * 16 + m16]);
      const float ff = sigm(gstg[(1 * 128 + row) * 16 + m16]);
      const float gg = tnh (gstg[(2 * 128 + row) * 16 + m16]);
      const float oo = sigm(gstg[(3 * 128 + row) * 16 + m16]);
      c1[r] = ff * c1[r] + ii * gg;
      h1g[((pout * 16 + g) * 144 + row) * 256 + m * 16 + m16] = f2bf(oo * tnh(c1[r]));
    }
    group_barrier(cnt1 + t, tid);                // h1_new visible group-wide

    // ---- phase C: d = gelu(h1_new @ W3^T + b3); out = d @ W4^T + b4 ----
    // member's 8 rows (m*8..m*8+7), dcol tile dct = v (16 cols per wave)
    {
      s8v W3f[8], A3[8];
      #pragma unroll
      for (int kk = 0; kk < 8; kk++)
        W3f[kk] = *(const s8v*)(img + 1048576 + v * 4096 + kk * 512 + (lane << 3));
      #pragma unroll
      for (int kk = 0; kk < 8; kk++)
        A3[kk] = *(const s8v*)(h1g + ((pout * 16 + g) * 144 + m * 8 + m16) * 256 + kk * 32 + q * 8);
      f4v ad = {0.f, 0.f, 0.f, 0.f};
      #pragma unroll
      for (int kk = 0; kk < 8; kk++) ad = mfma16(A3[kk], W3f[kk], ad);
      float p0[4], p1[4];
      #pragma unroll
      for (int r = 0; r < 4; r++){
        const float dv = gelu(ad[r] + b3c);
        p0[r] = dv * w40;
        p1[r] = dv * w41;
      }
      #pragma unroll
      for (int mk = 1; mk < 16; mk <<= 1)
        #pragma unroll
        for (int r = 0; r < 4; r++){
          p0[r] += __shfl_xor(p0[r], mk);
          p1[r] += __shfl_xor(p1[r], mk);
        }
      if (m16 == 0 && q < 2){
        #pragma unroll
        for (int r = 0; r < 4; r++){
          pstg[(v * 8 + q * 4 + r) * 2 + 0] = p0[r];
          pstg[(v * 8 + q * 4 + r) * 2 + 1] = p1[r];
        }
      }
    }
    __syncthreads();
    if (tid < 16){
      const int row = tid >> 1, o = tid & 1;
      float s = b4v;                              // b4[o] (lane&1 == o here)
      #pragma unroll
      for (int wv2 = 0; wv2 < 8; wv2++) s += pstg[(wv2 * 8 + row) * 2 + o];
      out[((size_t)(grow0 + m * 8 + row) * 256 + t) * 2 + o] = s;
    }
    // pstg reuse next step is separated by >=2 __syncthreads in phases A/B
  }
}

extern "C" void kernel_launch(void* const* d_in, const int* in_sizes, int n_in,
                              void* d_out, int out_size, void* d_ws, size_t ws_size,
                              hipStream_t stream)
{
  const float* x    = (const float*)d_in[0];
  const float* W1   = (const float*)d_in[1];
  const float* b1   = (const float*)d_in[2];
  const float* g1   = (const float*)d_in[3];
  const float* be1  = (const float*)d_in[4];
  const float* W2   = (const float*)d_in[5];
  const float* b2   = (const float*)d_in[6];
  const float* g2   = (const float*)d_in[7];
  const float* be2  = (const float*)d_in[8];
  const float* Wih0 = (const float*)d_in[9];
  const float* Whh0 = (const float*)d_in[10];
  const float* bih0 = (const float*)d_in[11];
  const float* bhh0 = (const float*)d_in[12];
  const float* Wih1 = (const float*)d_in[13];
  const float* Whh1 = (const float*)d_in[14];
  const float* bih1 = (const float*)d_in[15];
  const float* bhh1 = (const float*)d_in[16];
  const float* W3   = (const float*)d_in[17];
  const float* b3   = (const float*)d_in[18];
  const float* W4   = (const float*)d_in[19];
  const float* b4   = (const float*)d_in[20];

  short* wsb = (short*)d_ws;

  prep_kernel<<<4232, 256, 0, stream>>>(Wih0, Whh0, Wih1, Whh1, W3, W4, wsb);
  // zero enc/h/counters region: bytes [2*ENC_OFF, 2*CNT_OFF + 4*2*16*264)
  hipMemsetAsync((char*)d_ws + 2168832, 0, 5932032, stream);
  curve_rec<<<256, 512, 0, stream>>>(x, W1, b1, g1, be1, W2, b2, g2, be2,
                                     bih0, bhh0, bih1, bhh1, b3, b4, W4, wsb,
                                     (float*)d_out);
}

// Round 6
// 2600.714 us; speedup vs baseline: 11.9108x; 11.9108x over previous
//
#include <hip/hip_runtime.h>
#include <math.h>

// ---------------------------------------------------------------------------
// CurvePredictor R13: R12's skewed 16-way split with the coherence layer
// rebuilt on compiler-modeled relaxed agent-scope atomics.
// R12 post-mortem (NaN): inline-asm global loads returned dest regs with no
// internal waitcnt; the compiler doesn't model in-flight asm loads and may
// move/reuse the reg before the separate wait_vm0 -> garbage bf16 -> NaN.
// Also: enc lived inside h0 parity-1 (cross-block WAR at iter 0).
// R13:
//  - all cross-block h/enc traffic via __hip_atomic_load/store RELAXED AGENT
//    (LLVM emits the right sc bits for cross-XCD visibility AND tracks the
//    loads, inserting its own waitcnts; no cache-maintenance ops emitted).
//  - group barrier: drain vmcnt(0) (stores reach IC before arrive), relaxed
//    agent atomicAdd arrive, relaxed agent poll + s_sleep, finite failsafe.
//  - enc in its own ws region (WAR fixed).
//  - structure unchanged: iter s stages h0(s),h1(s-1) into LDS (once per
//    block), computes h0(s+1) and h1(s) with register-resident Whh0/Wih1/
//    Whh1 slices, decoder consumes h1(s-1), ONE group barrier per iter.
// LDS 131.6KB forces 1 block/CU; grid 256 = 256 CUs, all co-resident
// (R11 proved 256x512 co-residency at 1 block/CU on this part).
// ---------------------------------------------------------------------------

typedef short s8v __attribute__((ext_vector_type(8)));   // 8 x bf16
typedef float f4v __attribute__((ext_vector_type(4)));   // 4 x f32
typedef unsigned long long u64;

// ws layout (units: shorts)
#define IMG_SH   1084416                 // swizzled weight image
#define H0G_SH   (IMG_SH)                // h0g[2 par][16 g][64 tiles][512]
#define H1G_SH   (H0G_SH + 1048576)
#define CNT_SH   (H1G_SH + 1048576)      // u32 cnt[16][260] = 8320 shorts
#define ENC_SH   (CNT_SH + 8320)         // encg[16 g][64 tiles][512]

__device__ __forceinline__ f4v mfma16(s8v a, s8v b, f4v c){
  return __builtin_amdgcn_mfma_f32_16x16x32_bf16(a, b, c, 0, 0, 0);
}
__device__ __forceinline__ short f2bf(float f){
  unsigned u = __float_as_uint(f);
  u = u + 0x7FFFu + ((u >> 16) & 1u);
  return (short)(u >> 16);
}
__device__ __forceinline__ float wred(float v){
  #pragma unroll
  for (int o = 32; o; o >>= 1) v += __shfl_xor(v, o);
  return v;
}
__device__ __forceinline__ float sigm(float x){ return 1.0f / (1.0f + __expf(-x)); }
__device__ __forceinline__ float tnh(float x){
  x = fminf(15.0f, fmaxf(-15.0f, x));
  float e = __expf(2.0f * x);
  return (e - 1.0f) / (e + 1.0f);
}
__device__ __forceinline__ float gelu(float v){
  return 0.5f * v * (1.0f + erff(v * 0.70710678118654752440f));
}

// ---- coherent (agent/IC-level) access, compiler-modeled ----
__device__ __forceinline__ u64 ldc8(const u64* p){
  return __hip_atomic_load(p, __ATOMIC_RELAXED, __HIP_MEMORY_SCOPE_AGENT);
}
__device__ __forceinline__ void stc2(short* p, short v){
  __hip_atomic_store(p, v, __ATOMIC_RELAXED, __HIP_MEMORY_SCOPE_AGENT);
}
__device__ __forceinline__ void wbar(){                 // lgkm-only raw barrier
  asm volatile("s_waitcnt lgkmcnt(0)" ::: "memory");
  __builtin_amdgcn_s_barrier();
}
__device__ __forceinline__ void group_bar(unsigned* c, int tid){
  asm volatile("s_waitcnt vmcnt(0) lgkmcnt(0)" ::: "memory");  // data at IC first
  __builtin_amdgcn_s_barrier();
  if (tid == 0){
    __hip_atomic_fetch_add(c, 1u, __ATOMIC_RELAXED, __HIP_MEMORY_SCOPE_AGENT);
    unsigned it = 0;
    while (__hip_atomic_load(c, __ATOMIC_RELAXED, __HIP_MEMORY_SCOPE_AGENT) < 16u
           && ++it < (1u << 17))
      __builtin_amdgcn_s_sleep(4);        // failsafe: finite on bug
  }
  __builtin_amdgcn_s_barrier();
  asm volatile("" ::: "memory");          // no hoisting of post-barrier loads
}

// weight image: identical swizzle to R5-R12 (interior lane-linear lane*8):
// mats (1024x256): s*16384 + g*4096 + kk*512 + lane*8 + j ; lane=q*16+m16,
// col=s*16+m16, k=kk*32+q*8+j, gate-row=g*256+col.
// [0,262144) Wih0 [262144,524288) Whh0 [524288,786432) Wih1 [786432,1048576) Whh1
// W3 [128][256]: 1048576 + s2*4096 + kk*512 + lane*8
__global__ void prep_kernel(
    const float* __restrict__ Wih0, const float* __restrict__ Whh0,
    const float* __restrict__ Wih1, const float* __restrict__ Whh1,
    const float* __restrict__ W3,   const float* __restrict__ W4,
    short* __restrict__ wsb)
{
  const int i = blockIdx.x * 256 + threadIdx.x;
  if (i >= 1083392) return;
  float v;
  if (i < 1048576){
    const int seg = i >> 18;
    const int r   = i & 262143;
    const int s   = r >> 14;
    const int g   = (r >> 12) & 3;
    const int kk  = (r >> 9) & 7;
    const int q   = (r >> 7) & 3;
    const int m16 = (r >> 3) & 15;
    const int j   = r & 7;
    const int hid = s * 16 + m16;
    const int k   = kk * 32 + q * 8 + j;
    const float* mt = (seg == 0) ? Wih0 : (seg == 1) ? Whh0 : (seg == 2) ? Wih1 : Whh1;
    v = mt[(g * 256 + hid) * 256 + k];
  } else if (i < 1081344){
    const int r   = i - 1048576;
    const int s2  = r >> 12;
    const int kk  = (r >> 9) & 7;
    const int q   = (r >> 7) & 3;
    const int m16 = (r >> 3) & 15;
    const int j   = r & 7;
    v = W3[(s2 * 16 + m16) * 256 + kk * 32 + q * 8 + j];
  } else {
    const int r   = i - 1081344;
    const int kk  = (r >> 9) & 3;
    const int q   = (r >> 7) & 3;
    const int m16 = (r >> 3) & 15;
    const int j   = r & 7;
    const int k   = kk * 32 + q * 8 + j;
    v = (m16 < 2) ? W4[m16 * 128 + k] : 0.0f;
  }
  wsb[i] = f2bf(v);
}

// h/enc buffers are A-packed: element (row 0..127, col 0..255) at
//   tile = (row>>4)*8 + (col>>5); interior = (((col>>3)&3)*16 + (row&15))*8 + (col&7)
// so a gemm lane (q,m16) reads tile (rt*8+kk) at interior lane*8.

__global__ __launch_bounds__(512) void curve_rec(
    const float* __restrict__ x,
    const float* __restrict__ W1, const float* __restrict__ b1,
    const float* __restrict__ g1, const float* __restrict__ be1,
    const float* __restrict__ W2, const float* __restrict__ b2,
    const float* __restrict__ g2, const float* __restrict__ be2,
    const float* __restrict__ bih0, const float* __restrict__ bhh0,
    const float* __restrict__ bih1, const float* __restrict__ bhh1,
    const float* __restrict__ b3, const float* __restrict__ b4,
    const float* __restrict__ W4,
    short* __restrict__ wsb,
    float* __restrict__ out)
{
  const int tid  = threadIdx.x;
  const int v    = tid >> 6;          // wave 0..7
  const int lane = tid & 63;
  const int q    = lane >> 4;
  const int m16  = lane & 15;
  const int bid  = blockIdx.x;
  const int g    = bid & 15;          // group (128 batch rows)
  const int m    = bid >> 4;          // member (16 hidden cols)
  const int gate = v & 3;
  const int rh   = v >> 2;            // row-half (64 rows)

  const short* img = wsb;
  short* h0g  = wsb + H0G_SH;
  short* h1g  = wsb + H1G_SH;
  short* encg = wsb + ENC_SH;
  unsigned* cnt = (unsigned*)(wsb + CNT_SH) + g * 260;

  __shared__ __align__(16) short ldsH0[64 * 512];   // 64KB: h0 stage / G0 (f32)
  __shared__ __align__(16) short ldsX [64 * 512];   // 64KB: h1 stage / G1 (f32)
  __shared__ __align__(16) float pstg[128];

  // ---- persistent register-resident weight fragments (loaded once) ----
  s8v Bh0[8], Bi1[8], Bh1[8];
  #pragma unroll
  for (int kk = 0; kk < 8; kk++){
    const int off = m * 16384 + gate * 4096 + kk * 512 + (lane << 3);
    Bh0[kk] = *(const s8v*)(img + 262144 + off);
    Bi1[kk] = *(const s8v*)(img + 524288 + off);
    Bh1[kk] = *(const s8v*)(img + 786432 + off);
  }
  const float b3c = b3[v * 16 + m16];
  const float w40 = W4[v * 16 + m16];
  const float w41 = W4[128 + v * 16 + m16];
  const float b4o = b4[tid & 1];
  const int   n0  = gate * 256 + m * 16 + m16;
  const float bs1v = bih1[n0] + bhh1[n0];
  // pointwise packed-store constants (col = m*16+m16)
  const int colg = m * 16 + m16;
  const int tb = colg >> 5, qc = (colg >> 3) & 3, jc = colg & 7;
  // decoder A constants (row = m*8+m16)
  const int row3 = m * 8 + m16, rt3 = row3 >> 4, rin3 = row3 & 15;

  // ---- encoder: wave v computes batch row m*8+v of this group ----
  {
    const int row_l = m * 8 + v;
    const int r = g * 128 + row_l;
    float xv[5];
    #pragma unroll
    for (int k = 0; k < 5; k++) xv[k] = x[r * 5 + k];
    float a0 = b1[lane], a1 = b1[lane + 64];
    #pragma unroll
    for (int k = 0; k < 5; k++){
      a0 += xv[k] * W1[lane * 5 + k];
      a1 += xv[k] * W1[(lane + 64) * 5 + k];
    }
    a0 = gelu(a0); a1 = gelu(a1);
    float mean = wred(a0 + a1) * (1.0f / 128.0f);
    float d0 = a0 - mean, d1 = a1 - mean;
    float inv = rsqrtf(wred(d0 * d0 + d1 * d1) * (1.0f / 128.0f) + 1e-5f);
    float y0 = d0 * inv * g1[lane]      + be1[lane];
    float y1 = d1 * inv * g1[lane + 64] + be1[lane + 64];

    float acc2[4];
    #pragma unroll
    for (int uu = 0; uu < 4; uu++) acc2[uu] = b2[lane + 64 * uu];
    for (int k = 0; k < 64; k++){
      float v0 = __shfl(y0, k);
      float v1 = __shfl(y1, k);
      #pragma unroll
      for (int uu = 0; uu < 4; uu++){
        const float* wr = W2 + (lane + 64 * uu) * 128;
        acc2[uu] += v0 * wr[k] + v1 * wr[k + 64];
      }
    }
    #pragma unroll
    for (int uu = 0; uu < 4; uu++) acc2[uu] = gelu(acc2[uu]);
    float s = acc2[0] + acc2[1] + acc2[2] + acc2[3];
    mean = wred(s) * (1.0f / 256.0f);
    float vv = 0.0f;
    #pragma unroll
    for (int uu = 0; uu < 4; uu++){ float d = acc2[uu] - mean; vv += d * d; }
    inv = rsqrtf(wred(vv) * (1.0f / 256.0f) + 1e-5f);
    short* eb = encg + g * 32768;
    const int rt_e = row_l >> 4, rin_e = row_l & 15;
    const int qe = (lane >> 3) & 3, je = lane & 7;
    #pragma unroll
    for (int uu = 0; uu < 4; uu++){
      const int c = lane + 64 * uu;
      const int kk_e = c >> 5;
      const float e = (acc2[uu] - mean) * inv * g2[c] + be2[c];
      stc2(eb + (rt_e * 8 + kk_e) * 512 + (qe * 16 + rin_e) * 8 + je, f2bf(e));
    }
  }
  group_bar(cnt + 258, tid);                   // enc visible group-wide

  // ---- stage enc -> ldsH0; xp = enc @ Wih0_slice + (bih0+bhh0) ----
  {
    const u64* src = (const u64*)(encg + g * 32768);
    u64 t[16];
    #pragma unroll
    for (int u = 0; u < 16; u++) t[u] = ldc8(src + tid + u * 512);
    #pragma unroll
    for (int u = 0; u < 16; u++) ((u64*)ldsH0)[tid + u * 512] = t[u];
  }
  wbar();
  f4v xp[4];
  {
    s8v Wi0[8];
    #pragma unroll
    for (int kk = 0; kk < 8; kk++)
      Wi0[kk] = *(const s8v*)(img + m * 16384 + gate * 4096 + kk * 512 + (lane << 3));
    const float bi = bih0[n0] + bhh0[n0];
    #pragma unroll
    for (int rt = 0; rt < 4; rt++){ f4v t = {bi, bi, bi, bi}; xp[rt] = t; }
    const short* A0 = ldsH0 + rh * 16384 + (lane << 3);
    #pragma unroll
    for (int rt = 0; rt < 4; rt++)
      #pragma unroll
      for (int kk = 0; kk < 8; kk++)
        xp[rt] = mfma16(*(const s8v*)(A0 + (rt * 8 + kk) * 512), Wi0[kk], xp[rt]);
  }
  wbar();                                      // ldsH0 free for s=0 stage

  float c0[4] = {0.f,0.f,0.f,0.f}, c1[4] = {0.f,0.f,0.f,0.f};

  // ------------------ skewed recurrence: iter s in [0,257] ------------------
  // computes h0(s+1) [s<=255] and h1(s) [1<=s<=256]; decoder(h1(s-1)) [s>=2].
  #pragma unroll 1
  for (int s = 0; s <= 257; s++){
    // ---- stage h0(s) -> ldsH0, h1(s-1) -> ldsX (cooperative, IC once) ----
    {
      const u64* h0src = (const u64*)(h0g + ((s & 1) * 16 + g) * 32768);
      const u64* h1src = (const u64*)(h1g + ((((s + 1) & 1)) * 16 + g) * 32768);
      if (s <= 256){
        u64 t0[16];
        #pragma unroll
        for (int u = 0; u < 16; u++) t0[u] = ldc8(h0src + tid + u * 512);
        #pragma unroll
        for (int u = 0; u < 16; u++) ((u64*)ldsH0)[tid + u * 512] = t0[u];
      }
      if (s >= 1){
        u64 t1[16];
        #pragma unroll
        for (int u = 0; u < 16; u++) t1[u] = ldc8(h1src + tid + u * 512);
        #pragma unroll
        for (int u = 0; u < 16; u++) ((u64*)ldsX)[tid + u * 512] = t1[u];
      }
    }
    wbar();                                             // (1) stages visible

    // ---- merged gemms: acc0 = xp + h0@Bh0 ; acc1 = bs1 + h0@Bi1 + h1@Bh1 ----
    f4v acc0[4], acc1[4];
    #pragma unroll
    for (int rt = 0; rt < 4; rt++){
      acc0[rt] = xp[rt];
      f4v t = {bs1v, bs1v, bs1v, bs1v};
      acc1[rt] = t;
    }
    {
      const short* A0 = ldsH0 + rh * 16384 + (lane << 3);
      const short* A1 = ldsX  + rh * 16384 + (lane << 3);
      #pragma unroll
      for (int rt = 0; rt < 4; rt++)
        #pragma unroll
        for (int kk = 0; kk < 8; kk++){
          const s8v a = *(const s8v*)(A0 + (rt * 8 + kk) * 512);
          acc0[rt] = mfma16(a, Bh0[kk], acc0[rt]);
          acc1[rt] = mfma16(a, Bi1[kk], acc1[rt]);
        }
      #pragma unroll
      for (int rt = 0; rt < 4; rt++)
        #pragma unroll
        for (int kk = 0; kk < 8; kk++)
          acc1[rt] = mfma16(*(const s8v*)(A1 + (rt * 8 + kk) * 512), Bh1[kk], acc1[rt]);
    }
    wbar();                                             // (2) ldsH0 reads done

    // ---- decoder on h1(s-1) (from ldsX) + G0 write ----
    if (s >= 2){
      f4v ad = {0.f, 0.f, 0.f, 0.f};
      #pragma unroll
      for (int kk = 0; kk < 8; kk++){
        const s8v w3f = *(const s8v*)(img + 1048576 + v * 4096 + kk * 512 + (lane << 3));
        const s8v a3  = *(const s8v*)(ldsX + (rt3 * 8 + kk) * 512 + (q * 16 + rin3) * 8);
        ad = mfma16(a3, w3f, ad);
      }
      float p0[4], p1[4];
      #pragma unroll
      for (int r = 0; r < 4; r++){
        const float dv = gelu(ad[r] + b3c);
        p0[r] = dv * w40;
        p1[r] = dv * w41;
      }
      #pragma unroll
      for (int mk = 1; mk < 16; mk <<= 1)
        #pragma unroll
        for (int r = 0; r < 4; r++){
          p0[r] += __shfl_xor(p0[r], mk);
          p1[r] += __shfl_xor(p1[r], mk);
        }
      if (m16 == 0 && q < 2){
        #pragma unroll
        for (int r = 0; r < 4; r++){
          pstg[(v * 8 + q * 4 + r) * 2 + 0] = p0[r];
          pstg[(v * 8 + q * 4 + r) * 2 + 1] = p1[r];
        }
      }
    }
    {
      float* G0 = (float*)ldsH0;                        // overwrites h0 stage
      #pragma unroll
      for (int rt = 0; rt < 4; rt++)
        #pragma unroll
        for (int r = 0; r < 4; r++)
          G0[(gate * 128 + rh * 64 + rt * 16 + q * 4 + r) * 20 + m16] = acc0[rt][r];
    }
    wbar();                                             // (3) ldsX reads done, pstg visible

    {
      float* G1 = (float*)ldsX;                         // overwrites h1 stage
      #pragma unroll
      for (int rt = 0; rt < 4; rt++)
        #pragma unroll
        for (int r = 0; r < 4; r++)
          G1[(gate * 128 + rh * 64 + rt * 16 + q * 4 + r) * 20 + m16] = acc1[rt][r];
    }
    if (s >= 2 && tid < 16){
      const int row = tid >> 1, o = tid & 1;
      float sum = b4o;
      #pragma unroll
      for (int w2 = 0; w2 < 8; w2++) sum += pstg[(w2 * 8 + row) * 2 + o];
      out[((size_t)(g * 128 + m * 8 + row) * 256 + (s - 2)) * 2 + o] = sum;
    }
    wbar();                                             // (4) gates visible

    // ---- pointwise: thread owns rows v*16+q*4+r, col m*16+m16 ----
    if (s <= 255){
      const float* G0 = (const float*)ldsH0;
      short* hb = h0g + ((((s + 1) & 1)) * 16 + g) * 32768 + (v * 8 + tb) * 512 + qc * 128 + jc;
      #pragma unroll
      for (int r = 0; r < 4; r++){
        const int row = v * 16 + q * 4 + r;
        const float ii = sigm(G0[(0 * 128 + row) * 20 + m16]);
        const float ff = sigm(G0[(1 * 128 + row) * 20 + m16]);
        const float gg = tnh (G0[(2 * 128 + row) * 20 + m16]);
        const float oo = sigm(G0[(3 * 128 + row) * 20 + m16]);
        c0[r] = ff * c0[r] + ii * gg;
        stc2(hb + (q * 4 + r) * 8, f2bf(oo * tnh(c0[r])));
      }
    }
    if (s >= 1 && s <= 256){
      const float* G1 = (const float*)ldsX;
      short* hb = h1g + ((s & 1) * 16 + g) * 32768 + (v * 8 + tb) * 512 + qc * 128 + jc;
      #pragma unroll
      for (int r = 0; r < 4; r++){
        const int row = v * 16 + q * 4 + r;
        const float ii = sigm(G1[(0 * 128 + row) * 20 + m16]);
        const float ff = sigm(G1[(1 * 128 + row) * 20 + m16]);
        const float gg = tnh (G1[(2 * 128 + row) * 20 + m16]);
        const float oo = sigm(G1[(3 * 128 + row) * 20 + m16]);
        c1[r] = ff * c1[r] + ii * gg;
        stc2(hb + (q * 4 + r) * 8, f2bf(oo * tnh(c1[r])));
      }
    }

    if (s <= 256) group_bar(cnt + s, tid);              // publish h0(s+1), h1(s)
  }
}

extern "C" void kernel_launch(void* const* d_in, const int* in_sizes, int n_in,
                              void* d_out, int out_size, void* d_ws, size_t ws_size,
                              hipStream_t stream)
{
  const float* x    = (const float*)d_in[0];
  const float* W1   = (const float*)d_in[1];
  const float* b1   = (const float*)d_in[2];
  const float* g1   = (const float*)d_in[3];
  const float* be1  = (const float*)d_in[4];
  const float* W2   = (const float*)d_in[5];
  const float* b2   = (const float*)d_in[6];
  const float* g2   = (const float*)d_in[7];
  const float* be2  = (const float*)d_in[8];
  const float* Wih0 = (const float*)d_in[9];
  const float* Whh0 = (const float*)d_in[10];
  const float* bih0 = (const float*)d_in[11];
  const float* bhh0 = (const float*)d_in[12];
  const float* Wih1 = (const float*)d_in[13];
  const float* Whh1 = (const float*)d_in[14];
  const float* bih1 = (const float*)d_in[15];
  const float* bhh1 = (const float*)d_in[16];
  const float* W3   = (const float*)d_in[17];
  const float* b3   = (const float*)d_in[18];
  const float* W4   = (const float*)d_in[19];
  const float* b4   = (const float*)d_in[20];

  short* wsb = (short*)d_ws;

  prep_kernel<<<4232, 256, 0, stream>>>(Wih0, Whh0, Wih1, Whh1, W3, W4, wsb);
  // zero h0g + h1g + counters: bytes [2*H0G_SH, 2*H0G_SH + 4210944)
  hipMemsetAsync((char*)d_ws + 2168832, 0, 4210944, stream);
  curve_rec<<<256, 512, 0, stream>>>(x, W1, b1, g1, be1, W2, b2, g2, be2,
                                     bih0, bhh0, bih1, bhh1, b3, b4, W4, wsb,
                                     (float*)d_out);
}

// Round 7
// 2525.980 us; speedup vs baseline: 12.2632x; 1.0296x over previous
//
#include <hip/hip_runtime.h>
#include <math.h>

// ---------------------------------------------------------------------------
// CurvePredictor R14: R13 + coalesced h-exchange publication.
// R13 post-mortem: PASS @2800us warm. WRITE_SIZE 1.06GB = 2x ideal exchange
// volume -> the pointwise phase published h via 4096 scattered 2B agent
// stores per block/iter (write-through partial-line RMW at IC), and the
// vmcnt(0) drain at barrier entry waits for all of them on the serial path.
// R14: pointwise writes h bf16 to a 4KB-per-layer LDS gather (hstg); after
// one wbar each thread issues ONE 8B agent store per layer (each wave = one
// contiguous 512B chunk of the member's own slice). 4096x2B -> 1024x8B.
// Also: decoder MFMA moved next to the gemms (all ldsX reads before one
// wbar), G0+G1 written together. Same 4 wbars + 1 group_bar per iter.
// Everything else identical to R13 (structure proven: 16 groups x 16
// members, register-resident Whh0/Wih1/Whh1, relaxed agent atomics, skewed
// single-barrier iteration, 1 block/CU via >80KB LDS, grid 256 = #CUs).
// ---------------------------------------------------------------------------

typedef short s8v __attribute__((ext_vector_type(8)));   // 8 x bf16
typedef float f4v __attribute__((ext_vector_type(4)));   // 4 x f32
typedef unsigned long long u64;

// ws layout (units: shorts)
#define IMG_SH   1084416                 // swizzled weight image
#define H0G_SH   (IMG_SH)                // h0g[2 par][16 g][64 tiles][512]
#define H1G_SH   (H0G_SH + 1048576)
#define CNT_SH   (H1G_SH + 1048576)      // u32 cnt[16][260] = 8320 shorts
#define ENC_SH   (CNT_SH + 8320)         // encg[16 g][64 tiles][512]

__device__ __forceinline__ f4v mfma16(s8v a, s8v b, f4v c){
  return __builtin_amdgcn_mfma_f32_16x16x32_bf16(a, b, c, 0, 0, 0);
}
__device__ __forceinline__ short f2bf(float f){
  unsigned u = __float_as_uint(f);
  u = u + 0x7FFFu + ((u >> 16) & 1u);
  return (short)(u >> 16);
}
__device__ __forceinline__ float wred(float v){
  #pragma unroll
  for (int o = 32; o; o >>= 1) v += __shfl_xor(v, o);
  return v;
}
__device__ __forceinline__ float sigm(float x){ return 1.0f / (1.0f + __expf(-x)); }
__device__ __forceinline__ float tnh(float x){
  x = fminf(15.0f, fmaxf(-15.0f, x));
  float e = __expf(2.0f * x);
  return (e - 1.0f) / (e + 1.0f);
}
__device__ __forceinline__ float gelu(float v){
  return 0.5f * v * (1.0f + erff(v * 0.70710678118654752440f));
}

// ---- coherent (agent/IC-level) access, compiler-modeled ----
__device__ __forceinline__ u64 ldc8(const u64* p){
  return __hip_atomic_load(p, __ATOMIC_RELAXED, __HIP_MEMORY_SCOPE_AGENT);
}
__device__ __forceinline__ void stc2(short* p, short v){
  __hip_atomic_store(p, v, __ATOMIC_RELAXED, __HIP_MEMORY_SCOPE_AGENT);
}
__device__ __forceinline__ void stc8(u64* p, u64 v){
  __hip_atomic_store(p, v, __ATOMIC_RELAXED, __HIP_MEMORY_SCOPE_AGENT);
}
__device__ __forceinline__ void wbar(){                 // lgkm-only raw barrier
  asm volatile("s_waitcnt lgkmcnt(0)" ::: "memory");
  __builtin_amdgcn_s_barrier();
}
__device__ __forceinline__ void group_bar(unsigned* c, int tid){
  asm volatile("s_waitcnt vmcnt(0) lgkmcnt(0)" ::: "memory");  // data at IC first
  __builtin_amdgcn_s_barrier();
  if (tid == 0){
    __hip_atomic_fetch_add(c, 1u, __ATOMIC_RELAXED, __HIP_MEMORY_SCOPE_AGENT);
    unsigned it = 0;
    while (__hip_atomic_load(c, __ATOMIC_RELAXED, __HIP_MEMORY_SCOPE_AGENT) < 16u
           && ++it < (1u << 17))
      __builtin_amdgcn_s_sleep(4);        // failsafe: finite on bug
  }
  __builtin_amdgcn_s_barrier();
  asm volatile("" ::: "memory");          // no hoisting of post-barrier loads
}

// weight image: identical swizzle to R5-R13 (interior lane-linear lane*8):
// mats (1024x256): s*16384 + g*4096 + kk*512 + lane*8 + j ; lane=q*16+m16,
// col=s*16+m16, k=kk*32+q*8+j, gate-row=g*256+col.
// [0,262144) Wih0 [262144,524288) Whh0 [524288,786432) Wih1 [786432,1048576) Whh1
// W3 [128][256]: 1048576 + s2*4096 + kk*512 + lane*8
__global__ void prep_kernel(
    const float* __restrict__ Wih0, const float* __restrict__ Whh0,
    const float* __restrict__ Wih1, const float* __restrict__ Whh1,
    const float* __restrict__ W3,   const float* __restrict__ W4,
    short* __restrict__ wsb)
{
  const int i = blockIdx.x * 256 + threadIdx.x;
  if (i >= 1083392) return;
  float v;
  if (i < 1048576){
    const int seg = i >> 18;
    const int r   = i & 262143;
    const int s   = r >> 14;
    const int g   = (r >> 12) & 3;
    const int kk  = (r >> 9) & 7;
    const int q   = (r >> 7) & 3;
    const int m16 = (r >> 3) & 15;
    const int j   = r & 7;
    const int hid = s * 16 + m16;
    const int k   = kk * 32 + q * 8 + j;
    const float* mt = (seg == 0) ? Wih0 : (seg == 1) ? Whh0 : (seg == 2) ? Wih1 : Whh1;
    v = mt[(g * 256 + hid) * 256 + k];
  } else if (i < 1081344){
    const int r   = i - 1048576;
    const int s2  = r >> 12;
    const int kk  = (r >> 9) & 7;
    const int q   = (r >> 7) & 3;
    const int m16 = (r >> 3) & 15;
    const int j   = r & 7;
    v = W3[(s2 * 16 + m16) * 256 + kk * 32 + q * 8 + j];
  } else {
    const int r   = i - 1081344;
    const int kk  = (r >> 9) & 3;
    const int q   = (r >> 7) & 3;
    const int m16 = (r >> 3) & 15;
    const int j   = r & 7;
    const int k   = kk * 32 + q * 8 + j;
    v = (m16 < 2) ? W4[m16 * 128 + k] : 0.0f;
  }
  wsb[i] = f2bf(v);
}

// h/enc buffers are A-packed: element (row 0..127, col 0..255) at
//   tile = (row>>4)*8 + (col>>5); interior = (((col>>3)&3)*16 + (row&15))*8 + (col&7)
// so a gemm lane (q,m16) reads tile (rt*8+kk) at interior lane*8.
// A member's own slice (16 cols starting m*16) per row-tile rt is ONE
// contiguous 512B block at (rt*8 + (m>>1))*512 + ((2m)&3)*128 shorts.

__global__ __launch_bounds__(512) void curve_rec(
    const float* __restrict__ x,
    const float* __restrict__ W1, const float* __restrict__ b1,
    const float* __restrict__ g1, const float* __restrict__ be1,
    const float* __restrict__ W2, const float* __restrict__ b2,
    const float* __restrict__ g2, const float* __restrict__ be2,
    const float* __restrict__ bih0, const float* __restrict__ bhh0,
    const float* __restrict__ bih1, const float* __restrict__ bhh1,
    const float* __restrict__ b3, const float* __restrict__ b4,
    const float* __restrict__ W4,
    short* __restrict__ wsb,
    float* __restrict__ out)
{
  const int tid  = threadIdx.x;
  const int v    = tid >> 6;          // wave 0..7
  const int lane = tid & 63;
  const int q    = lane >> 4;
  const int m16  = lane & 15;
  const int bid  = blockIdx.x;
  const int g    = bid & 15;          // group (128 batch rows)
  const int m    = bid >> 4;          // member (16 hidden cols)
  const int gate = v & 3;
  const int rh   = v >> 2;            // row-half (64 rows)

  const short* img = wsb;
  short* h0g  = wsb + H0G_SH;
  short* h1g  = wsb + H1G_SH;
  short* encg = wsb + ENC_SH;
  unsigned* cnt = (unsigned*)(wsb + CNT_SH) + g * 260;

  __shared__ __align__(16) short ldsH0[64 * 512];   // 64KB: h0 stage / G0 (f32)
  __shared__ __align__(16) short ldsX [64 * 512];   // 64KB: h1 stage / G1 (f32)
  __shared__ __align__(16) u64   hstg[2][512];      // 8KB: coalesced h gather
  __shared__ __align__(16) float pstg[128];

  // ---- persistent register-resident weight fragments (loaded once) ----
  s8v Bh0[8], Bi1[8], Bh1[8];
  #pragma unroll
  for (int kk = 0; kk < 8; kk++){
    const int off = m * 16384 + gate * 4096 + kk * 512 + (lane << 3);
    Bh0[kk] = *(const s8v*)(img + 262144 + off);
    Bi1[kk] = *(const s8v*)(img + 524288 + off);
    Bh1[kk] = *(const s8v*)(img + 786432 + off);
  }
  const float b3c = b3[v * 16 + m16];
  const float w40 = W4[v * 16 + m16];
  const float w41 = W4[128 + v * 16 + m16];
  const float b4o = b4[tid & 1];
  const int   n0  = gate * 256 + m * 16 + m16;
  const float bs1v = bih1[n0] + bhh1[n0];
  // coalesced-store constants: member slice chunk base (shorts)
  const int tbm  = m >> 1;
  const int qsel = (2 * m) & 3;
  // decoder A constants (row = m*8+m16)
  const int row3 = m * 8 + m16, rt3 = row3 >> 4, rin3 = row3 & 15;

  // ---- encoder: wave v computes batch row m*8+v of this group ----
  {
    const int row_l = m * 8 + v;
    const int r = g * 128 + row_l;
    float xv[5];
    #pragma unroll
    for (int k = 0; k < 5; k++) xv[k] = x[r * 5 + k];
    float a0 = b1[lane], a1 = b1[lane + 64];
    #pragma unroll
    for (int k = 0; k < 5; k++){
      a0 += xv[k] * W1[lane * 5 + k];
      a1 += xv[k] * W1[(lane + 64) * 5 + k];
    }
    a0 = gelu(a0); a1 = gelu(a1);
    float mean = wred(a0 + a1) * (1.0f / 128.0f);
    float d0 = a0 - mean, d1 = a1 - mean;
    float inv = rsqrtf(wred(d0 * d0 + d1 * d1) * (1.0f / 128.0f) + 1e-5f);
    float y0 = d0 * inv * g1[lane]      + be1[lane];
    float y1 = d1 * inv * g1[lane + 64] + be1[lane + 64];

    float acc2[4];
    #pragma unroll
    for (int uu = 0; uu < 4; uu++) acc2[uu] = b2[lane + 64 * uu];
    for (int k = 0; k < 64; k++){
      float v0 = __shfl(y0, k);
      float v1 = __shfl(y1, k);
      #pragma unroll
      for (int uu = 0; uu < 4; uu++){
        const float* wr = W2 + (lane + 64 * uu) * 128;
        acc2[uu] += v0 * wr[k] + v1 * wr[k + 64];
      }
    }
    #pragma unroll
    for (int uu = 0; uu < 4; uu++) acc2[uu] = gelu(acc2[uu]);
    float s = acc2[0] + acc2[1] + acc2[2] + acc2[3];
    mean = wred(s) * (1.0f / 256.0f);
    float vv = 0.0f;
    #pragma unroll
    for (int uu = 0; uu < 4; uu++){ float d = acc2[uu] - mean; vv += d * d; }
    inv = rsqrtf(wred(vv) * (1.0f / 256.0f) + 1e-5f);
    short* eb = encg + g * 32768;
    const int rt_e = row_l >> 4, rin_e = row_l & 15;
    const int qe = (lane >> 3) & 3, je = lane & 7;
    #pragma unroll
    for (int uu = 0; uu < 4; uu++){
      const int c = lane + 64 * uu;
      const int kk_e = c >> 5;
      const float e = (acc2[uu] - mean) * inv * g2[c] + be2[c];
      stc2(eb + (rt_e * 8 + kk_e) * 512 + (qe * 16 + rin_e) * 8 + je, f2bf(e));
    }
  }
  group_bar(cnt + 258, tid);                   // enc visible group-wide

  // ---- stage enc -> ldsH0; xp = enc @ Wih0_slice + (bih0+bhh0) ----
  {
    const u64* src = (const u64*)(encg + g * 32768);
    u64 t[16];
    #pragma unroll
    for (int u = 0; u < 16; u++) t[u] = ldc8(src + tid + u * 512);
    #pragma unroll
    for (int u = 0; u < 16; u++) ((u64*)ldsH0)[tid + u * 512] = t[u];
  }
  wbar();
  f4v xp[4];
  {
    s8v Wi0[8];
    #pragma unroll
    for (int kk = 0; kk < 8; kk++)
      Wi0[kk] = *(const s8v*)(img + m * 16384 + gate * 4096 + kk * 512 + (lane << 3));
    const float bi = bih0[n0] + bhh0[n0];
    #pragma unroll
    for (int rt = 0; rt < 4; rt++){ f4v t = {bi, bi, bi, bi}; xp[rt] = t; }
    const short* A0 = ldsH0 + rh * 16384 + (lane << 3);
    #pragma unroll
    for (int rt = 0; rt < 4; rt++)
      #pragma unroll
      for (int kk = 0; kk < 8; kk++)
        xp[rt] = mfma16(*(const s8v*)(A0 + (rt * 8 + kk) * 512), Wi0[kk], xp[rt]);
  }
  wbar();                                      // ldsH0 free for s=0 stage

  float c0[4] = {0.f,0.f,0.f,0.f}, c1[4] = {0.f,0.f,0.f,0.f};

  // ------------------ skewed recurrence: iter s in [0,257] ------------------
  // computes h0(s+1) [s<=255] and h1(s) [1<=s<=256]; decoder(h1(s-1)) [s>=2].
  #pragma unroll 1
  for (int s = 0; s <= 257; s++){
    const bool dec = (s >= 2);

    // ---- stage h0(s) -> ldsH0, h1(s-1) -> ldsX (cooperative, IC once) ----
    {
      const u64* h0src = (const u64*)(h0g + ((s & 1) * 16 + g) * 32768);
      const u64* h1src = (const u64*)(h1g + ((((s + 1) & 1)) * 16 + g) * 32768);
      if (s <= 256){
        u64 t0[16];
        #pragma unroll
        for (int u = 0; u < 16; u++) t0[u] = ldc8(h0src + tid + u * 512);
        #pragma unroll
        for (int u = 0; u < 16; u++) ((u64*)ldsH0)[tid + u * 512] = t0[u];
      }
      if (s >= 1){
        u64 t1[16];
        #pragma unroll
        for (int u = 0; u < 16; u++) t1[u] = ldc8(h1src + tid + u * 512);
        #pragma unroll
        for (int u = 0; u < 16; u++) ((u64*)ldsX)[tid + u * 512] = t1[u];
      }
    }
    wbar();                                             // (A) stages visible

    // ---- merged gemms: acc0 = xp + h0@Bh0 ; acc1 = bs1 + h0@Bi1 + h1@Bh1 ----
    f4v acc0[4], acc1[4];
    #pragma unroll
    for (int rt = 0; rt < 4; rt++){
      acc0[rt] = xp[rt];
      f4v t = {bs1v, bs1v, bs1v, bs1v};
      acc1[rt] = t;
    }
    {
      const short* A0 = ldsH0 + rh * 16384 + (lane << 3);
      const short* A1 = ldsX  + rh * 16384 + (lane << 3);
      #pragma unroll
      for (int rt = 0; rt < 4; rt++)
        #pragma unroll
        for (int kk = 0; kk < 8; kk++){
          const s8v a = *(const s8v*)(A0 + (rt * 8 + kk) * 512);
          acc0[rt] = mfma16(a, Bh0[kk], acc0[rt]);
          acc1[rt] = mfma16(a, Bi1[kk], acc1[rt]);
        }
      #pragma unroll
      for (int rt = 0; rt < 4; rt++)
        #pragma unroll
        for (int kk = 0; kk < 8; kk++)
          acc1[rt] = mfma16(*(const s8v*)(A1 + (rt * 8 + kk) * 512), Bh1[kk], acc1[rt]);
    }

    // ---- decoder gemm + reduce on h1(s-1) (reads ldsX; before wbar B) ----
    float p0[4], p1[4];
    if (dec){
      f4v ad = {0.f, 0.f, 0.f, 0.f};
      #pragma unroll
      for (int kk = 0; kk < 8; kk++){
        const s8v w3f = *(const s8v*)(img + 1048576 + v * 4096 + kk * 512 + (lane << 3));
        const s8v a3  = *(const s8v*)(ldsX + (rt3 * 8 + kk) * 512 + (q * 16 + rin3) * 8);
        ad = mfma16(a3, w3f, ad);
      }
      #pragma unroll
      for (int r = 0; r < 4; r++){
        const float dv = gelu(ad[r] + b3c);
        p0[r] = dv * w40;
        p1[r] = dv * w41;
      }
      #pragma unroll
      for (int mk = 1; mk < 16; mk <<= 1)
        #pragma unroll
        for (int r = 0; r < 4; r++){
          p0[r] += __shfl_xor(p0[r], mk);
          p1[r] += __shfl_xor(p1[r], mk);
        }
    }
    wbar();                                             // (B) all stage reads done

    // ---- G0 -> ldsH0, G1 -> ldsX (f32, stride 20), pstg ----
    {
      float* G0 = (float*)ldsH0;
      float* G1 = (float*)ldsX;
      #pragma unroll
      for (int rt = 0; rt < 4; rt++)
        #pragma unroll
        for (int r = 0; r < 4; r++){
          G0[(gate * 128 + rh * 64 + rt * 16 + q * 4 + r) * 20 + m16] = acc0[rt][r];
          G1[(gate * 128 + rh * 64 + rt * 16 + q * 4 + r) * 20 + m16] = acc1[rt][r];
        }
    }
    if (dec && m16 == 0 && q < 2){
      #pragma unroll
      for (int r = 0; r < 4; r++){
        pstg[(v * 8 + q * 4 + r) * 2 + 0] = p0[r];
        pstg[(v * 8 + q * 4 + r) * 2 + 1] = p1[r];
      }
    }
    wbar();                                             // (C) gates + pstg visible

    // ---- pointwise -> hstg (LDS gather); out-write ----
    if (s <= 255){
      const float* G0 = (const float*)ldsH0;
      short* hs0 = (short*)&hstg[0][0];
      #pragma unroll
      for (int r = 0; r < 4; r++){
        const int row = v * 16 + q * 4 + r;
        const float ii = sigm(G0[(0 * 128 + row) * 20 + m16]);
        const float ff = sigm(G0[(1 * 128 + row) * 20 + m16]);
        const float gg = tnh (G0[(2 * 128 + row) * 20 + m16]);
        const float oo = sigm(G0[(3 * 128 + row) * 20 + m16]);
        c0[r] = ff * c0[r] + ii * gg;
        hs0[v * 256 + (m16 >> 3) * 128 + (q * 4 + r) * 8 + (m16 & 7)] =
            f2bf(oo * tnh(c0[r]));
      }
    }
    if (s >= 1 && s <= 256){
      const float* G1 = (const float*)ldsX;
      short* hs1 = (short*)&hstg[1][0];
      #pragma unroll
      for (int r = 0; r < 4; r++){
        const int row = v * 16 + q * 4 + r;
        const float ii = sigm(G1[(0 * 128 + row) * 20 + m16]);
        const float ff = sigm(G1[(1 * 128 + row) * 20 + m16]);
        const float gg = tnh (G1[(2 * 128 + row) * 20 + m16]);
        const float oo = sigm(G1[(3 * 128 + row) * 20 + m16]);
        c1[r] = ff * c1[r] + ii * gg;
        hs1[v * 256 + (m16 >> 3) * 128 + (q * 4 + r) * 8 + (m16 & 7)] =
            f2bf(oo * tnh(c1[r]));
      }
    }
    if (dec && tid < 16){
      const int row = tid >> 1, o = tid & 1;
      float sum = b4o;
      #pragma unroll
      for (int w2 = 0; w2 < 8; w2++) sum += pstg[(w2 * 8 + row) * 2 + o];
      out[((size_t)(g * 128 + m * 8 + row) * 256 + (s - 2)) * 2 + o] = sum;
    }
    wbar();                                             // (D) hstg complete

    // ---- coalesced publication: 1 u64 agent store per thread per layer ----
    // wave v stores the contiguous 512B chunk (rows v*16..+15, own 16 cols)
    if (s <= 255){
      short* dst = h0g + ((((s + 1) & 1)) * 16 + g) * 32768
                 + v * 4096 + tbm * 512 + qsel * 128 + lane * 4;
      stc8((u64*)dst, hstg[0][tid]);
    }
    if (s >= 1 && s <= 256){
      short* dst = h1g + ((s & 1) * 16 + g) * 32768
                 + v * 4096 + tbm * 512 + qsel * 128 + lane * 4;
      stc8((u64*)dst, hstg[1][tid]);
    }

    if (s <= 256) group_bar(cnt + s, tid);              // publish h0(s+1), h1(s)
  }
}

extern "C" void kernel_launch(void* const* d_in, const int* in_sizes, int n_in,
                              void* d_out, int out_size, void* d_ws, size_t ws_size,
                              hipStream_t stream)
{
  const float* x    = (const float*)d_in[0];
  const float* W1   = (const float*)d_in[1];
  const float* b1   = (const float*)d_in[2];
  const float* g1   = (const float*)d_in[3];
  const float* be1  = (const float*)d_in[4];
  const float* W2   = (const float*)d_in[5];
  const float* b2   = (const float*)d_in[6];
  const float* g2   = (const float*)d_in[7];
  const float* be2  = (const float*)d_in[8];
  const float* Wih0 = (const float*)d_in[9];
  const float* Whh0 = (const float*)d_in[10];
  const float* bih0 = (const float*)d_in[11];
  const float* bhh0 = (const float*)d_in[12];
  const float* Wih1 = (const float*)d_in[13];
  const float* Whh1 = (const float*)d_in[14];
  const float* bih1 = (const float*)d_in[15];
  const float* bhh1 = (const float*)d_in[16];
  const float* W3   = (const float*)d_in[17];
  const float* b3   = (const float*)d_in[18];
  const float* W4   = (const float*)d_in[19];
  const float* b4   = (const float*)d_in[20];

  short* wsb = (short*)d_ws;

  prep_kernel<<<4232, 256, 0, stream>>>(Wih0, Whh0, Wih1, Whh1, W3, W4, wsb);
  // zero h0g + h1g + counters: bytes [2*H0G_SH, 2*H0G_SH + 4210944)
  hipMemsetAsync((char*)d_ws + 2168832, 0, 4210944, stream);
  curve_rec<<<256, 512, 0, stream>>>(x, W1, b1, g1, be1, W2, b2, g2, be2,
                                     bih0, bhh0, bih1, bhh1, b3, b4, W4, wsb,
                                     (float*)d_out);
}

// Round 8
// 2189.515 us; speedup vs baseline: 14.1477x; 1.1537x over previous
//
#include <hip/hip_runtime.h>
#include <math.h>

// ---------------------------------------------------------------------------
// CurvePredictor R15: R14 regrouped to 32 groups x 8 members (R=64, C=32).
// R14 post-mortem: WRITE halved as predicted but dur -4% -> stores weren't
// the critical path; iter budget is staging-IC + barrier RTT + skew.
// R15 (same proven skeleton: register-resident Whh0/Wih1/Whh1, relaxed
// agent atomics, skewed single-barrier iteration, 1 block/CU, grid=256):
//  - groups of 64 rows x members of 32 cols: staged bytes/block/iter halve
//    (64KB), barrier degree halves (8 arrivals), per-wave MFMA unchanged
//    (wave = gate x col-half; same weight image, s-slice = 2m+ch).
//  - pointwise ownership matched to the A-packed layout: each thread's 4
//    cells pack into ONE u64 -> direct stc8 publication (hstg + its wbar
//    + its bank conflicts deleted).
//  - group barrier split arrive/wait: decoder tail (gelu/shuffle/pstg/out)
//    runs between arrive and poll, hiding it under peer skew. W3 frags
//    preloaded to registers (8 fewer global loads/iter).
// ---------------------------------------------------------------------------

typedef short s8v __attribute__((ext_vector_type(8)));   // 8 x bf16
typedef float f4v __attribute__((ext_vector_type(4)));   // 4 x f32
typedef unsigned long long u64;

// ws layout (units: shorts)
#define IMG_SH   1084416                 // swizzled weight image
#define H0G_SH   (IMG_SH)                // h0g[2 par][32 g][32 tiles][512]
#define H1G_SH   (H0G_SH + 1048576)
#define CNT_SH   (H1G_SH + 1048576)      // u32 cnt[32][260] = 16640 shorts
#define ENC_SH   (CNT_SH + 16640)        // encg[32 g][32 tiles][512]

__device__ __forceinline__ f4v mfma16(s8v a, s8v b, f4v c){
  return __builtin_amdgcn_mfma_f32_16x16x32_bf16(a, b, c, 0, 0, 0);
}
__device__ __forceinline__ short f2bf(float f){
  unsigned u = __float_as_uint(f);
  u = u + 0x7FFFu + ((u >> 16) & 1u);
  return (short)(u >> 16);
}
__device__ __forceinline__ float wred(float v){
  #pragma unroll
  for (int o = 32; o; o >>= 1) v += __shfl_xor(v, o);
  return v;
}
__device__ __forceinline__ float sigm(float x){ return 1.0f / (1.0f + __expf(-x)); }
__device__ __forceinline__ float tnh(float x){
  x = fminf(15.0f, fmaxf(-15.0f, x));
  float e = __expf(2.0f * x);
  return (e - 1.0f) / (e + 1.0f);
}
__device__ __forceinline__ float gelu(float v){
  return 0.5f * v * (1.0f + erff(v * 0.70710678118654752440f));
}

// ---- coherent (agent/IC-level) access, compiler-modeled ----
__device__ __forceinline__ u64 ldc8(const u64* p){
  return __hip_atomic_load(p, __ATOMIC_RELAXED, __HIP_MEMORY_SCOPE_AGENT);
}
__device__ __forceinline__ void stc2(short* p, short v){
  __hip_atomic_store(p, v, __ATOMIC_RELAXED, __HIP_MEMORY_SCOPE_AGENT);
}
__device__ __forceinline__ void stc8(u64* p, u64 v){
  __hip_atomic_store(p, v, __ATOMIC_RELAXED, __HIP_MEMORY_SCOPE_AGENT);
}
__device__ __forceinline__ void wbar(){                 // lgkm-only raw barrier
  asm volatile("s_waitcnt lgkmcnt(0)" ::: "memory");
  __builtin_amdgcn_s_barrier();
}
// arrive: all waves' global stores drained, then one agent-relaxed add
__device__ __forceinline__ void arrive_bar(unsigned* c, int tid){
  asm volatile("s_waitcnt vmcnt(0) lgkmcnt(0)" ::: "memory");
  __builtin_amdgcn_s_barrier();
  if (tid == 0)
    __hip_atomic_fetch_add(c, 1u, __ATOMIC_RELAXED, __HIP_MEMORY_SCOPE_AGENT);
}
// wait: poll to 8 members, then release the block
__device__ __forceinline__ void wait_bar(unsigned* c, int tid){
  if (tid == 0){
    unsigned it = 0;
    while (__hip_atomic_load(c, __ATOMIC_RELAXED, __HIP_MEMORY_SCOPE_AGENT) < 8u
           && ++it < (1u << 17))
      __builtin_amdgcn_s_sleep(4);        // failsafe: finite on bug
  }
  __builtin_amdgcn_s_barrier();
  asm volatile("" ::: "memory");          // no hoisting of post-barrier loads
}

// weight image: identical swizzle to R5-R14 (interior lane-linear lane*8):
// mats (1024x256): s*16384 + g*4096 + kk*512 + lane*8 + j ; lane=q*16+m16,
// col=s*16+m16, k=kk*32+q*8+j, gate-row=g*256+col.
// [0,262144) Wih0 [262144,524288) Whh0 [524288,786432) Wih1 [786432,1048576) Whh1
// W3 [128][256]: 1048576 + s2*4096 + kk*512 + lane*8
__global__ void prep_kernel(
    const float* __restrict__ Wih0, const float* __restrict__ Whh0,
    const float* __restrict__ Wih1, const float* __restrict__ Whh1,
    const float* __restrict__ W3,   const float* __restrict__ W4,
    short* __restrict__ wsb)
{
  const int i = blockIdx.x * 256 + threadIdx.x;
  if (i >= 1083392) return;
  float v;
  if (i < 1048576){
    const int seg = i >> 18;
    const int r   = i & 262143;
    const int s   = r >> 14;
    const int g   = (r >> 12) & 3;
    const int kk  = (r >> 9) & 7;
    const int q   = (r >> 7) & 3;
    const int m16 = (r >> 3) & 15;
    const int j   = r & 7;
    const int hid = s * 16 + m16;
    const int k   = kk * 32 + q * 8 + j;
    const float* mt = (seg == 0) ? Wih0 : (seg == 1) ? Whh0 : (seg == 2) ? Wih1 : Whh1;
    v = mt[(g * 256 + hid) * 256 + k];
  } else if (i < 1081344){
    const int r   = i - 1048576;
    const int s2  = r >> 12;
    const int kk  = (r >> 9) & 7;
    const int q   = (r >> 7) & 3;
    const int m16 = (r >> 3) & 15;
    const int j   = r & 7;
    v = W3[(s2 * 16 + m16) * 256 + kk * 32 + q * 8 + j];
  } else {
    const int r   = i - 1081344;
    const int kk  = (r >> 9) & 3;
    const int q   = (r >> 7) & 3;
    const int m16 = (r >> 3) & 15;
    const int j   = r & 7;
    const int k   = kk * 32 + q * 8 + j;
    v = (m16 < 2) ? W4[m16 * 128 + k] : 0.0f;
  }
  wsb[i] = f2bf(v);
}

// h/enc buffers are A-packed (64 rows x 256 cols -> 32 tiles x 512 shorts):
//   tile = (row>>4)*8 + (col>>5); interior = (((col>>3)&3)*16 + (row&15))*8 + (col&7)
// gemm lane (q,m16) reads tile (rt*8+kk) at interior lane*8 (contiguous).
// Member m's slice per layer = tiles (rt*8+m), rt=0..3 -> 4 contiguous 1KB
// chunks; pointwise thread tid owns exactly u64 index (tid&127) of tile
// (tid>>7)*8+m, so publication is one stc8 per thread per layer.

__global__ __launch_bounds__(512) void curve_rec(
    const float* __restrict__ x,
    const float* __restrict__ W1, const float* __restrict__ b1,
    const float* __restrict__ g1, const float* __restrict__ be1,
    const float* __restrict__ W2, const float* __restrict__ b2,
    const float* __restrict__ g2, const float* __restrict__ be2,
    const float* __restrict__ bih0, const float* __restrict__ bhh0,
    const float* __restrict__ bih1, const float* __restrict__ bhh1,
    const float* __restrict__ b3, const float* __restrict__ b4,
    const float* __restrict__ W4,
    short* __restrict__ wsb,
    float* __restrict__ out)
{
  const int tid  = threadIdx.x;
  const int v    = tid >> 6;          // wave 0..7
  const int lane = tid & 63;
  const int q    = lane >> 4;
  const int m16  = lane & 15;
  const int bid  = blockIdx.x;
  const int g    = bid & 31;          // group (64 batch rows)
  const int m    = bid >> 5;          // member (32 hidden cols)
  const int gate = v & 3;
  const int ch   = v >> 2;            // col-half of the member's 32-col slice

  const short* img = wsb;
  short* h0g  = wsb + H0G_SH;
  short* h1g  = wsb + H1G_SH;
  short* encg = wsb + ENC_SH;
  unsigned* cnt = (unsigned*)(wsb + CNT_SH) + g * 260;

  __shared__ __align__(16) short ldsH0[20608];   // 40.25KB: h0 stage / G0 f32
  __shared__ __align__(16) short ldsX [20608];   // 40.25KB: h1 stage / G1 f32
  __shared__ __align__(16) float pstg[128];      // total 82.9KB -> 1 block/CU

  // ---- persistent register-resident weight fragments (loaded once) ----
  s8v Bh0[8], Bi1[8], Bh1[8], W3r[8];
  const int sIdx = 2 * m + ch;        // 16-col image slice index
  #pragma unroll
  for (int kk = 0; kk < 8; kk++){
    const int off = sIdx * 16384 + gate * 4096 + kk * 512 + (lane << 3);
    Bh0[kk] = *(const s8v*)(img + 262144 + off);
    Bi1[kk] = *(const s8v*)(img + 524288 + off);
    Bh1[kk] = *(const s8v*)(img + 786432 + off);
    W3r[kk] = *(const s8v*)(img + 1048576 + v * 4096 + kk * 512 + (lane << 3));
  }
  const float b3c = b3[v * 16 + m16];
  const float w40 = W4[v * 16 + m16];
  const float w41 = W4[128 + v * 16 + m16];
  const float b4o = b4[tid & 1];
  const int   n0  = gate * 256 + m * 32 + ch * 16 + m16;
  const float bs1v = bih1[n0] + bhh1[n0];
  // decoder A constants (rows m*8 + m16-window; rows>=8 feed discarded lanes)
  const int row3 = m * 8 + m16, rt3 = row3 >> 4, rin3 = row3 & 15;
  // pointwise ownership: thread tid -> 4 cells = one u64 of the A-packed slice
  const int rt_p = tid >> 7, rem = tid & 127;
  const int cq_p = (rem >> 5) & 3, r16p = (rem >> 1) & 15, c4h = rem & 1;
  const int rowp  = rt_p * 16 + r16p;            // row within group (0..63)
  const int coltp = cq_p * 8 + c4h * 4;          // col within member slice
  const int pub_off = (rt_p * 8 + m) * 512 + rem * 4;   // shorts in layer chunk

  // ---- encoder: wave v computes batch row m*8+v of this group ----
  {
    const int row_l = m * 8 + v;
    const int r = g * 64 + row_l;
    float xv[5];
    #pragma unroll
    for (int k = 0; k < 5; k++) xv[k] = x[r * 5 + k];
    float a0 = b1[lane], a1 = b1[lane + 64];
    #pragma unroll
    for (int k = 0; k < 5; k++){
      a0 += xv[k] * W1[lane * 5 + k];
      a1 += xv[k] * W1[(lane + 64) * 5 + k];
    }
    a0 = gelu(a0); a1 = gelu(a1);
    float mean = wred(a0 + a1) * (1.0f / 128.0f);
    float d0 = a0 - mean, d1 = a1 - mean;
    float inv = rsqrtf(wred(d0 * d0 + d1 * d1) * (1.0f / 128.0f) + 1e-5f);
    float y0 = d0 * inv * g1[lane]      + be1[lane];
    float y1 = d1 * inv * g1[lane + 64] + be1[lane + 64];

    float acc2[4];
    #pragma unroll
    for (int uu = 0; uu < 4; uu++) acc2[uu] = b2[lane + 64 * uu];
    for (int k = 0; k < 64; k++){
      float v0 = __shfl(y0, k);
      float v1 = __shfl(y1, k);
      #pragma unroll
      for (int uu = 0; uu < 4; uu++){
        const float* wr = W2 + (lane + 64 * uu) * 128;
        acc2[uu] += v0 * wr[k] + v1 * wr[k + 64];
      }
    }
    #pragma unroll
    for (int uu = 0; uu < 4; uu++) acc2[uu] = gelu(acc2[uu]);
    float s = acc2[0] + acc2[1] + acc2[2] + acc2[3];
    mean = wred(s) * (1.0f / 256.0f);
    float vv = 0.0f;
    #pragma unroll
    for (int uu = 0; uu < 4; uu++){ float d = acc2[uu] - mean; vv += d * d; }
    inv = rsqrtf(wred(vv) * (1.0f / 256.0f) + 1e-5f);
    short* eb = encg + g * 16384;
    const int rt_e = row_l >> 4, rin_e = row_l & 15;
    const int qe = (lane >> 3) & 3, je = lane & 7;
    #pragma unroll
    for (int uu = 0; uu < 4; uu++){
      const int c = lane + 64 * uu;
      const float e = (acc2[uu] - mean) * inv * g2[c] + be2[c];
      stc2(eb + (rt_e * 8 + (c >> 5)) * 512 + (qe * 16 + rin_e) * 8 + je, f2bf(e));
    }
  }
  arrive_bar(cnt + 258, tid);
  wait_bar(cnt + 258, tid);                    // enc visible group-wide

  // ---- stage enc -> ldsH0; xp = enc @ Wih0_slice + (bih0+bhh0) ----
  {
    const u64* src = (const u64*)(encg + g * 16384);
    u64 t[8];
    #pragma unroll
    for (int u = 0; u < 8; u++) t[u] = ldc8(src + tid + u * 512);
    #pragma unroll
    for (int u = 0; u < 8; u++) ((u64*)ldsH0)[tid + u * 512] = t[u];
  }
  wbar();
  f4v xp[4];
  {
    s8v Wi0[8];
    #pragma unroll
    for (int kk = 0; kk < 8; kk++)
      Wi0[kk] = *(const s8v*)(img + sIdx * 16384 + gate * 4096 + kk * 512 + (lane << 3));
    const float bi = bih0[n0] + bhh0[n0];
    #pragma unroll
    for (int rt = 0; rt < 4; rt++){ f4v t = {bi, bi, bi, bi}; xp[rt] = t; }
    const short* A0 = ldsH0 + (lane << 3);
    #pragma unroll
    for (int rt = 0; rt < 4; rt++)
      #pragma unroll
      for (int kk = 0; kk < 8; kk++)
        xp[rt] = mfma16(*(const s8v*)(A0 + (rt * 8 + kk) * 512), Wi0[kk], xp[rt]);
  }
  wbar();                                      // ldsH0 free for s=0 stage

  float c0[4] = {0.f,0.f,0.f,0.f}, c1[4] = {0.f,0.f,0.f,0.f};

  // ------------------ skewed recurrence: iter s in [0,257] ------------------
  // computes h0(s+1) [s<=255] and h1(s) [1<=s<=256]; decoder(h1(s-1)) [s>=2].
  #pragma unroll 1
  for (int s = 0; s <= 257; s++){
    const bool dec = (s >= 2);

    // ---- stage h0(s) -> ldsH0, h1(s-1) -> ldsX (8 u64 each, IC once) ----
    {
      const u64* h0src = (const u64*)(h0g + ((s & 1) * 32 + g) * 16384);
      const u64* h1src = (const u64*)(h1g + ((((s + 1) & 1)) * 32 + g) * 16384);
      if (s <= 256){
        u64 t0[8];
        #pragma unroll
        for (int u = 0; u < 8; u++) t0[u] = ldc8(h0src + tid + u * 512);
        #pragma unroll
        for (int u = 0; u < 8; u++) ((u64*)ldsH0)[tid + u * 512] = t0[u];
      }
      if (s >= 1){
        u64 t1[8];
        #pragma unroll
        for (int u = 0; u < 8; u++) t1[u] = ldc8(h1src + tid + u * 512);
        #pragma unroll
        for (int u = 0; u < 8; u++) ((u64*)ldsX)[tid + u * 512] = t1[u];
      }
    }
    wbar();                                             // (A) stages visible

    // ---- merged gemms: acc0 = xp + h0@Bh0 ; acc1 = bs1 + h0@Bi1 + h1@Bh1 ----
    f4v acc0[4], acc1[4];
    #pragma unroll
    for (int rt = 0; rt < 4; rt++){
      acc0[rt] = xp[rt];
      f4v t = {bs1v, bs1v, bs1v, bs1v};
      acc1[rt] = t;
    }
    {
      const short* A0 = ldsH0 + (lane << 3);
      const short* A1 = ldsX  + (lane << 3);
      #pragma unroll
      for (int rt = 0; rt < 4; rt++)
        #pragma unroll
        for (int kk = 0; kk < 8; kk++){
          const s8v a = *(const s8v*)(A0 + (rt * 8 + kk) * 512);
          acc0[rt] = mfma16(a, Bh0[kk], acc0[rt]);
          acc1[rt] = mfma16(a, Bi1[kk], acc1[rt]);
        }
      #pragma unroll
      for (int rt = 0; rt < 4; rt++)
        #pragma unroll
        for (int kk = 0; kk < 8; kk++)
          acc1[rt] = mfma16(*(const s8v*)(A1 + (rt * 8 + kk) * 512), Bh1[kk], acc1[rt]);
    }
    // decoder MFMA on h1(s-1) (reads ldsX; must precede wbar B)
    f4v ad = {0.f, 0.f, 0.f, 0.f};
    if (dec){
      #pragma unroll
      for (int kk = 0; kk < 8; kk++){
        const s8v a3 = *(const s8v*)(ldsX + (rt3 * 8 + kk) * 512 + (q * 16 + rin3) * 8);
        ad = mfma16(a3, W3r[kk], ad);
      }
    }
    wbar();                                             // (B) stage reads done

    // ---- G0 -> ldsH0, G1 -> ldsX (f32, stride 36) ----
    {
      float* G0 = (float*)ldsH0;
      float* G1 = (float*)ldsX;
      #pragma unroll
      for (int rt = 0; rt < 4; rt++)
        #pragma unroll
        for (int r = 0; r < 4; r++){
          const int row = rt * 16 + q * 4 + r;
          G0[(gate * 64 + row) * 36 + ch * 16 + m16] = acc0[rt][r];
          G1[(gate * 64 + row) * 36 + ch * 16 + m16] = acc1[rt][r];
        }
    }
    wbar();                                             // (C) gates visible

    // ---- pointwise + direct-packed publication (1 stc8 / thread / layer) --
    if (s <= 255){
      const float* G0 = (const float*)ldsH0;
      const f4v gi = *(const f4v*)&G0[(0 * 64 + rowp) * 36 + coltp];
      const f4v gf = *(const f4v*)&G0[(1 * 64 + rowp) * 36 + coltp];
      const f4v gg = *(const f4v*)&G0[(2 * 64 + rowp) * 36 + coltp];
      const f4v go = *(const f4v*)&G0[(3 * 64 + rowp) * 36 + coltp];
      u64 pk = 0;
      #pragma unroll
      for (int j = 0; j < 4; j++){
        const float ii = sigm(gi[j]), ff = sigm(gf[j]);
        const float ga = tnh(gg[j]),  oo = sigm(go[j]);
        c0[j] = ff * c0[j] + ii * ga;
        pk |= (u64)(unsigned short)f2bf(oo * tnh(c0[j])) << (16 * j);
      }
      stc8((u64*)(h0g + ((((s + 1) & 1)) * 32 + g) * 16384 + pub_off), pk);
    }
    if (s >= 1 && s <= 256){
      const float* G1 = (const float*)ldsX;
      const f4v gi = *(const f4v*)&G1[(0 * 64 + rowp) * 36 + coltp];
      const f4v gf = *(const f4v*)&G1[(1 * 64 + rowp) * 36 + coltp];
      const f4v gg = *(const f4v*)&G1[(2 * 64 + rowp) * 36 + coltp];
      const f4v go = *(const f4v*)&G1[(3 * 64 + rowp) * 36 + coltp];
      u64 pk = 0;
      #pragma unroll
      for (int j = 0; j < 4; j++){
        const float ii = sigm(gi[j]), ff = sigm(gf[j]);
        const float ga = tnh(gg[j]),  oo = sigm(go[j]);
        c1[j] = ff * c1[j] + ii * ga;
        pk |= (u64)(unsigned short)f2bf(oo * tnh(c1[j])) << (16 * j);
      }
      stc8((u64*)(h1g + ((s & 1) * 32 + g) * 16384 + pub_off), pk);
    }

    if (s <= 256) arrive_bar(cnt + s, tid);             // publish + arrive

    // ---- decoder tail (hidden under peer skew): gelu/reduce/pstg/out ----
    if (dec){
      float p0[4], p1[4];
      #pragma unroll
      for (int r = 0; r < 4; r++){
        const float dv = gelu(ad[r] + b3c);
        p0[r] = dv * w40;
        p1[r] = dv * w41;
      }
      #pragma unroll
      for (int mk = 1; mk < 16; mk <<= 1)
        #pragma unroll
        for (int r = 0; r < 4; r++){
          p0[r] += __shfl_xor(p0[r], mk);
          p1[r] += __shfl_xor(p1[r], mk);
        }
      if (m16 == 0 && q < 2){
        #pragma unroll
        for (int r = 0; r < 4; r++){
          pstg[(v * 8 + q * 4 + r) * 2 + 0] = p0[r];
          pstg[(v * 8 + q * 4 + r) * 2 + 1] = p1[r];
        }
      }
    }
    wbar();                                             // pstg visible
    if (dec && tid < 16){
      const int row = tid >> 1, o = tid & 1;
      float sum = b4o;
      #pragma unroll
      for (int w2 = 0; w2 < 8; w2++) sum += pstg[(w2 * 8 + row) * 2 + o];
      out[((size_t)(g * 64 + m * 8 + row) * 256 + (s - 2)) * 2 + o] = sum;
    }

    if (s <= 256) wait_bar(cnt + s, tid);               // h0(s+1), h1(s) ready
  }
}

extern "C" void kernel_launch(void* const* d_in, const int* in_sizes, int n_in,
                              void* d_out, int out_size, void* d_ws, size_t ws_size,
                              hipStream_t stream)
{
  const float* x    = (const float*)d_in[0];
  const float* W1   = (const float*)d_in[1];
  const float* b1   = (const float*)d_in[2];
  const float* g1   = (const float*)d_in[3];
  const float* be1  = (const float*)d_in[4];
  const float* W2   = (const float*)d_in[5];
  const float* b2   = (const float*)d_in[6];
  const float* g2   = (const float*)d_in[7];
  const float* be2  = (const float*)d_in[8];
  const float* Wih0 = (const float*)d_in[9];
  const float* Whh0 = (const float*)d_in[10];
  const float* bih0 = (const float*)d_in[11];
  const float* bhh0 = (const float*)d_in[12];
  const float* Wih1 = (const float*)d_in[13];
  const float* Whh1 = (const float*)d_in[14];
  const float* bih1 = (const float*)d_in[15];
  const float* bhh1 = (const float*)d_in[16];
  const float* W3   = (const float*)d_in[17];
  const float* b3   = (const float*)d_in[18];
  const float* W4   = (const float*)d_in[19];
  const float* b4   = (const float*)d_in[20];

  short* wsb = (short*)d_ws;

  prep_kernel<<<4232, 256, 0, stream>>>(Wih0, Whh0, Wih1, Whh1, W3, W4, wsb);
  // zero h0g + h1g + counters: bytes [2*H0G_SH, +2*(1048576*2+16640))
  hipMemsetAsync((char*)d_ws + 2168832, 0, 4227584, stream);
  curve_rec<<<256, 512, 0, stream>>>(x, W1, b1, g1, be1, W2, b2, g2, be2,
                                     bih0, bhh0, bih1, bhh1, b3, b4, W4, wsb,
                                     (float*)d_out);
}

// Round 9
// 2111.931 us; speedup vs baseline: 14.6675x; 1.0367x over previous
//
#include <hip/hip_runtime.h>
#include <math.h>

// ---------------------------------------------------------------------------
// CurvePredictor R16: R15 + dedicated gate-exchange LDS + stage-latency
// hiding + rcp transcendentals.
// R15 post-mortem: 2326us warm (9.0us/iter). Serial path = exposed IC stage
// latency + 3 wbars + G-exchange + divide-heavy pointwise + barrier RTT.
// (4-gates-per-wave rejected: B-frags are per-gate -> 4x weight VGPR.)
// R16:
//  - G0/G1 in their own LDS region (total 139.8KB, still 1 block/CU):
//    stage-read/G-write WAR barrier removed; budget respent as a stage
//    split: issue t0+t1 loads, write h0, wbar, run A0-half gemms (64 MFMA)
//    while t1's IC latency drains, write h1, wbar, finish. Latency hidden.
//  - sigm/tnh use __builtin_amdgcn_rcpf (1ulp) instead of full divides:
//    ~200 VALU/thread/iter removed; bf16-irrelevant precision change.
//  - s_sleep(2) poll for finer barrier release.
// Everything else identical to R15 (proven): 32 groups x 8 members,
// register-resident Whh0/Wih1/Whh1/W3, relaxed agent atomics, skewed
// single-barrier iteration, direct-packed u64 publication, grid=256.
// ---------------------------------------------------------------------------

typedef short s8v __attribute__((ext_vector_type(8)));   // 8 x bf16
typedef float f4v __attribute__((ext_vector_type(4)));   // 4 x f32
typedef unsigned long long u64;

// ws layout (units: shorts)
#define IMG_SH   1084416                 // swizzled weight image
#define H0G_SH   (IMG_SH)                // h0g[2 par][32 g][32 tiles][512]
#define H1G_SH   (H0G_SH + 1048576)
#define CNT_SH   (H1G_SH + 1048576)      // u32 cnt[32][260] = 16640 shorts
#define ENC_SH   (CNT_SH + 16640)        // encg[32 g][32 tiles][512]

__device__ __forceinline__ f4v mfma16(s8v a, s8v b, f4v c){
  return __builtin_amdgcn_mfma_f32_16x16x32_bf16(a, b, c, 0, 0, 0);
}
__device__ __forceinline__ short f2bf(float f){
  unsigned u = __float_as_uint(f);
  u = u + 0x7FFFu + ((u >> 16) & 1u);
  return (short)(u >> 16);
}
__device__ __forceinline__ float wred(float v){
  #pragma unroll
  for (int o = 32; o; o >>= 1) v += __shfl_xor(v, o);
  return v;
}
__device__ __forceinline__ float rcpf(float x){ return __builtin_amdgcn_rcpf(x); }
__device__ __forceinline__ float sigm(float x){ return rcpf(1.0f + __expf(-x)); }
__device__ __forceinline__ float tnh(float x){
  x = fminf(15.0f, fmaxf(-15.0f, x));
  float e = __expf(2.0f * x);
  return (e - 1.0f) * rcpf(e + 1.0f);
}
__device__ __forceinline__ float gelu(float v){
  return 0.5f * v * (1.0f + erff(v * 0.70710678118654752440f));
}

// ---- coherent (agent/IC-level) access, compiler-modeled ----
__device__ __forceinline__ u64 ldc8(const u64* p){
  return __hip_atomic_load(p, __ATOMIC_RELAXED, __HIP_MEMORY_SCOPE_AGENT);
}
__device__ __forceinline__ void stc2(short* p, short v){
  __hip_atomic_store(p, v, __ATOMIC_RELAXED, __HIP_MEMORY_SCOPE_AGENT);
}
__device__ __forceinline__ void stc8(u64* p, u64 v){
  __hip_atomic_store(p, v, __ATOMIC_RELAXED, __HIP_MEMORY_SCOPE_AGENT);
}
__device__ __forceinline__ void wbar(){                 // lgkm-only raw barrier
  asm volatile("s_waitcnt lgkmcnt(0)" ::: "memory");
  __builtin_amdgcn_s_barrier();
}
// arrive: all waves' global stores drained, then one agent-relaxed add
__device__ __forceinline__ void arrive_bar(unsigned* c, int tid){
  asm volatile("s_waitcnt vmcnt(0) lgkmcnt(0)" ::: "memory");
  __builtin_amdgcn_s_barrier();
  if (tid == 0)
    __hip_atomic_fetch_add(c, 1u, __ATOMIC_RELAXED, __HIP_MEMORY_SCOPE_AGENT);
}
// wait: poll to 8 members, then release the block
__device__ __forceinline__ void wait_bar(unsigned* c, int tid){
  if (tid == 0){
    unsigned it = 0;
    while (__hip_atomic_load(c, __ATOMIC_RELAXED, __HIP_MEMORY_SCOPE_AGENT) < 8u
           && ++it < (1u << 18))
      __builtin_amdgcn_s_sleep(2);        // failsafe: finite on bug
  }
  __builtin_amdgcn_s_barrier();
  asm volatile("" ::: "memory");          // no hoisting of post-barrier loads
}

// weight image: identical swizzle to R5-R15 (interior lane-linear lane*8):
// mats (1024x256): s*16384 + g*4096 + kk*512 + lane*8 + j ; lane=q*16+m16,
// col=s*16+m16, k=kk*32+q*8+j, gate-row=g*256+col.
// [0,262144) Wih0 [262144,524288) Whh0 [524288,786432) Wih1 [786432,1048576) Whh1
// W3 [128][256]: 1048576 + s2*4096 + kk*512 + lane*8
__global__ void prep_kernel(
    const float* __restrict__ Wih0, const float* __restrict__ Whh0,
    const float* __restrict__ Wih1, const float* __restrict__ Whh1,
    const float* __restrict__ W3,   const float* __restrict__ W4,
    short* __restrict__ wsb)
{
  const int i = blockIdx.x * 256 + threadIdx.x;
  if (i >= 1083392) return;
  float v;
  if (i < 1048576){
    const int seg = i >> 18;
    const int r   = i & 262143;
    const int s   = r >> 14;
    const int g   = (r >> 12) & 3;
    const int kk  = (r >> 9) & 7;
    const int q   = (r >> 7) & 3;
    const int m16 = (r >> 3) & 15;
    const int j   = r & 7;
    const int hid = s * 16 + m16;
    const int k   = kk * 32 + q * 8 + j;
    const float* mt = (seg == 0) ? Wih0 : (seg == 1) ? Whh0 : (seg == 2) ? Wih1 : Whh1;
    v = mt[(g * 256 + hid) * 256 + k];
  } else if (i < 1081344){
    const int r   = i - 1048576;
    const int s2  = r >> 12;
    const int kk  = (r >> 9) & 7;
    const int q   = (r >> 7) & 3;
    const int m16 = (r >> 3) & 15;
    const int j   = r & 7;
    v = W3[(s2 * 16 + m16) * 256 + kk * 32 + q * 8 + j];
  } else {
    const int r   = i - 1081344;
    const int kk  = (r >> 9) & 3;
    const int q   = (r >> 7) & 3;
    const int m16 = (r >> 3) & 15;
    const int j   = r & 7;
    const int k   = kk * 32 + q * 8 + j;
    v = (m16 < 2) ? W4[m16 * 128 + k] : 0.0f;
  }
  wsb[i] = f2bf(v);
}

// h/enc buffers are A-packed (64 rows x 256 cols -> 32 tiles x 512 shorts):
//   tile = (row>>4)*8 + (col>>5); interior = (((col>>3)&3)*16 + (row&15))*8 + (col&7)
// gemm lane (q,m16) reads tile (rt*8+kk) at interior lane*8 (contiguous).
// Pointwise thread tid owns exactly u64 index (tid&127) of tile (tid>>7)*8+m,
// so publication is one stc8 per thread per layer (proven in R15).

__global__ __launch_bounds__(512) void curve_rec(
    const float* __restrict__ x,
    const float* __restrict__ W1, const float* __restrict__ b1,
    const float* __restrict__ g1, const float* __restrict__ be1,
    const float* __restrict__ W2, const float* __restrict__ b2,
    const float* __restrict__ g2, const float* __restrict__ be2,
    const float* __restrict__ bih0, const float* __restrict__ bhh0,
    const float* __restrict__ bih1, const float* __restrict__ bhh1,
    const float* __restrict__ b3, const float* __restrict__ b4,
    const float* __restrict__ W4,
    short* __restrict__ wsb,
    float* __restrict__ out)
{
  const int tid  = threadIdx.x;
  const int v    = tid >> 6;          // wave 0..7
  const int lane = tid & 63;
  const int q    = lane >> 4;
  const int m16  = lane & 15;
  const int bid  = blockIdx.x;
  const int g    = bid & 31;          // group (64 batch rows)
  const int m    = bid >> 5;          // member (32 hidden cols)
  const int gate = v & 3;
  const int ch   = v >> 2;            // col-half of the member's 32-col slice

  const short* img = wsb;
  short* h0g  = wsb + H0G_SH;
  short* h1g  = wsb + H1G_SH;
  short* encg = wsb + ENC_SH;
  unsigned* cnt = (unsigned*)(wsb + CNT_SH) + g * 260;

  __shared__ __align__(16) short ldsH0[16384];   // 32KB: h0 stage
  __shared__ __align__(16) short ldsX [16384];   // 32KB: h1 stage
  __shared__ __align__(16) float Gst[2][256 * 36]; // 72KB: gate exchange
  __shared__ __align__(16) float pstg[128];      // total 139.8KB -> 1 blk/CU

  // ---- persistent register-resident weight fragments (loaded once) ----
  s8v Bh0[8], Bi1[8], Bh1[8], W3r[8];
  const int sIdx = 2 * m + ch;        // 16-col image slice index
  #pragma unroll
  for (int kk = 0; kk < 8; kk++){
    const int off = sIdx * 16384 + gate * 4096 + kk * 512 + (lane << 3);
    Bh0[kk] = *(const s8v*)(img + 262144 + off);
    Bi1[kk] = *(const s8v*)(img + 524288 + off);
    Bh1[kk] = *(const s8v*)(img + 786432 + off);
    W3r[kk] = *(const s8v*)(img + 1048576 + v * 4096 + kk * 512 + (lane << 3));
  }
  const float b3c = b3[v * 16 + m16];
  const float w40 = W4[v * 16 + m16];
  const float w41 = W4[128 + v * 16 + m16];
  const float b4o = b4[tid & 1];
  const int   n0  = gate * 256 + m * 32 + ch * 16 + m16;
  const float bs1v = bih1[n0] + bhh1[n0];
  // decoder A constants (rows m*8 + m16-window; rows>=8 feed discarded lanes)
  const int row3 = m * 8 + m16, rt3 = row3 >> 4, rin3 = row3 & 15;
  // pointwise ownership: thread tid -> 4 cells = one u64 of the A-packed slice
  const int rt_p = tid >> 7, rem = tid & 127;
  const int cq_p = (rem >> 5) & 3, r16p = (rem >> 1) & 15, c4h = rem & 1;
  const int rowp  = rt_p * 16 + r16p;            // row within group (0..63)
  const int coltp = cq_p * 8 + c4h * 4;          // col within member slice
  const int pub_off = (rt_p * 8 + m) * 512 + rem * 4;   // shorts in layer chunk

  // ---- encoder: wave v computes batch row m*8+v of this group ----
  {
    const int row_l = m * 8 + v;
    const int r = g * 64 + row_l;
    float xv[5];
    #pragma unroll
    for (int k = 0; k < 5; k++) xv[k] = x[r * 5 + k];
    float a0 = b1[lane], a1 = b1[lane + 64];
    #pragma unroll
    for (int k = 0; k < 5; k++){
      a0 += xv[k] * W1[lane * 5 + k];
      a1 += xv[k] * W1[(lane + 64) * 5 + k];
    }
    a0 = gelu(a0); a1 = gelu(a1);
    float mean = wred(a0 + a1) * (1.0f / 128.0f);
    float d0 = a0 - mean, d1 = a1 - mean;
    float inv = rsqrtf(wred(d0 * d0 + d1 * d1) * (1.0f / 128.0f) + 1e-5f);
    float y0 = d0 * inv * g1[lane]      + be1[lane];
    float y1 = d1 * inv * g1[lane + 64] + be1[lane + 64];

    float acc2[4];
    #pragma unroll
    for (int uu = 0; uu < 4; uu++) acc2[uu] = b2[lane + 64 * uu];
    for (int k = 0; k < 64; k++){
      float v0 = __shfl(y0, k);
      float v1 = __shfl(y1, k);
      #pragma unroll
      for (int uu = 0; uu < 4; uu++){
        const float* wr = W2 + (lane + 64 * uu) * 128;
        acc2[uu] += v0 * wr[k] + v1 * wr[k + 64];
      }
    }
    #pragma unroll
    for (int uu = 0; uu < 4; uu++) acc2[uu] = gelu(acc2[uu]);
    float s = acc2[0] + acc2[1] + acc2[2] + acc2[3];
    mean = wred(s) * (1.0f / 256.0f);
    float vv = 0.0f;
    #pragma unroll
    for (int uu = 0; uu < 4; uu++){ float d = acc2[uu] - mean; vv += d * d; }
    inv = rsqrtf(wred(vv) * (1.0f / 256.0f) + 1e-5f);
    short* eb = encg + g * 16384;
    const int rt_e = row_l >> 4, rin_e = row_l & 15;
    const int qe = (lane >> 3) & 3, je = lane & 7;
    #pragma unroll
    for (int uu = 0; uu < 4; uu++){
      const int c = lane + 64 * uu;
      const float e = (acc2[uu] - mean) * inv * g2[c] + be2[c];
      stc2(eb + (rt_e * 8 + (c >> 5)) * 512 + (qe * 16 + rin_e) * 8 + je, f2bf(e));
    }
  }
  arrive_bar(cnt + 258, tid);
  wait_bar(cnt + 258, tid);                    // enc visible group-wide

  // ---- stage enc -> ldsH0; xp = enc @ Wih0_slice + (bih0+bhh0) ----
  {
    const u64* src = (const u64*)(encg + g * 16384);
    u64 t[8];
    #pragma unroll
    for (int u = 0; u < 8; u++) t[u] = ldc8(src + tid + u * 512);
    #pragma unroll
    for (int u = 0; u < 8; u++) ((u64*)ldsH0)[tid + u * 512] = t[u];
  }
  wbar();
  f4v xp[4];
  {
    s8v Wi0[8];
    #pragma unroll
    for (int kk = 0; kk < 8; kk++)
      Wi0[kk] = *(const s8v*)(img + sIdx * 16384 + gate * 4096 + kk * 512 + (lane << 3));
    const float bi = bih0[n0] + bhh0[n0];
    #pragma unroll
    for (int rt = 0; rt < 4; rt++){ f4v t = {bi, bi, bi, bi}; xp[rt] = t; }
    const short* A0 = ldsH0 + (lane << 3);
    #pragma unroll
    for (int rt = 0; rt < 4; rt++)
      #pragma unroll
      for (int kk = 0; kk < 8; kk++)
        xp[rt] = mfma16(*(const s8v*)(A0 + (rt * 8 + kk) * 512), Wi0[kk], xp[rt]);
  }
  wbar();                                      // ldsH0 free for s=0 stage

  float c0[4] = {0.f,0.f,0.f,0.f}, c1[4] = {0.f,0.f,0.f,0.f};

  // ------------------ skewed recurrence: iter s in [0,257] ------------------
  // computes h0(s+1) [s<=255] and h1(s) [1<=s<=256]; decoder(h1(s-1)) [s>=2].
  #pragma unroll 1
  for (int s = 0; s <= 257; s++){
    const bool dec = (s >= 2);

    // ---- issue both stage load sets (16 in flight), write h0 only ----
    const u64* h0src = (const u64*)(h0g + ((s & 1) * 32 + g) * 16384);
    const u64* h1src = (const u64*)(h1g + ((((s + 1) & 1)) * 32 + g) * 16384);
    u64 t0[8], t1[8];
    if (s <= 256){
      #pragma unroll
      for (int u = 0; u < 8; u++) t0[u] = ldc8(h0src + tid + u * 512);
    }
    if (s >= 1){
      #pragma unroll
      for (int u = 0; u < 8; u++) t1[u] = ldc8(h1src + tid + u * 512);
    }
    if (s <= 256){
      #pragma unroll
      for (int u = 0; u < 8; u++) ((u64*)ldsH0)[tid + u * 512] = t0[u];
    }
    wbar();                                             // (A1) h0 staged

    // ---- A0-half gemms (hide t1's IC latency under 64 MFMAs) ----
    f4v acc0[4], acc1[4];
    #pragma unroll
    for (int rt = 0; rt < 4; rt++){
      acc0[rt] = xp[rt];
      f4v t = {bs1v, bs1v, bs1v, bs1v};
      acc1[rt] = t;
    }
    {
      const short* A0 = ldsH0 + (lane << 3);
      #pragma unroll
      for (int rt = 0; rt < 4; rt++)
        #pragma unroll
        for (int kk = 0; kk < 8; kk++){
          const s8v a = *(const s8v*)(A0 + (rt * 8 + kk) * 512);
          acc0[rt] = mfma16(a, Bh0[kk], acc0[rt]);
          acc1[rt] = mfma16(a, Bi1[kk], acc1[rt]);
        }
    }
    if (s >= 1){
      #pragma unroll
      for (int u = 0; u < 8; u++) ((u64*)ldsX)[tid + u * 512] = t1[u];
    }
    wbar();                                             // (A2) h1 staged

    // ---- A1-half: acc1 += h1@Bh1 ; decoder MFMA on h1(s-1) ----
    {
      const short* A1 = ldsX + (lane << 3);
      #pragma unroll
      for (int rt = 0; rt < 4; rt++)
        #pragma unroll
        for (int kk = 0; kk < 8; kk++)
          acc1[rt] = mfma16(*(const s8v*)(A1 + (rt * 8 + kk) * 512), Bh1[kk], acc1[rt]);
    }
    f4v ad = {0.f, 0.f, 0.f, 0.f};
    if (dec){
      #pragma unroll
      for (int kk = 0; kk < 8; kk++){
        const s8v a3 = *(const s8v*)(ldsX + (rt3 * 8 + kk) * 512 + (q * 16 + rin3) * 8);
        ad = mfma16(a3, W3r[kk], ad);
      }
    }

    // ---- G0/G1 -> dedicated region (no WAR vs stages: no barrier here) ----
    {
      #pragma unroll
      for (int rt = 0; rt < 4; rt++)
        #pragma unroll
        for (int r = 0; r < 4; r++){
          const int row = rt * 16 + q * 4 + r;
          Gst[0][(gate * 64 + row) * 36 + ch * 16 + m16] = acc0[rt][r];
          Gst[1][(gate * 64 + row) * 36 + ch * 16 + m16] = acc1[rt][r];
        }
    }
    wbar();                                             // (C) gates visible

    // ---- pointwise + direct-packed publication (1 stc8 / thread / layer) --
    if (s <= 255){
      const float* G0 = &Gst[0][0];
      const f4v gi = *(const f4v*)&G0[(0 * 64 + rowp) * 36 + coltp];
      const f4v gf = *(const f4v*)&G0[(1 * 64 + rowp) * 36 + coltp];
      const f4v gg = *(const f4v*)&G0[(2 * 64 + rowp) * 36 + coltp];
      const f4v go = *(const f4v*)&G0[(3 * 64 + rowp) * 36 + coltp];
      u64 pk = 0;
      #pragma unroll
      for (int j = 0; j < 4; j++){
        const float ii = sigm(gi[j]), ff = sigm(gf[j]);
        const float ga = tnh(gg[j]),  oo = sigm(go[j]);
        c0[j] = ff * c0[j] + ii * ga;
        pk |= (u64)(unsigned short)f2bf(oo * tnh(c0[j])) << (16 * j);
      }
      stc8((u64*)(h0g + ((((s + 1) & 1)) * 32 + g) * 16384 + pub_off), pk);
    }
    if (s >= 1 && s <= 256){
      const float* G1 = &Gst[1][0];
      const f4v gi = *(const f4v*)&G1[(0 * 64 + rowp) * 36 + coltp];
      const f4v gf = *(const f4v*)&G1[(1 * 64 + rowp) * 36 + coltp];
      const f4v gg = *(const f4v*)&G1[(2 * 64 + rowp) * 36 + coltp];
      const f4v go = *(const f4v*)&G1[(3 * 64 + rowp) * 36 + coltp];
      u64 pk = 0;
      #pragma unroll
      for (int j = 0; j < 4; j++){
        const float ii = sigm(gi[j]), ff = sigm(gf[j]);
        const float ga = tnh(gg[j]),  oo = sigm(go[j]);
        c1[j] = ff * c1[j] + ii * ga;
        pk |= (u64)(unsigned short)f2bf(oo * tnh(c1[j])) << (16 * j);
      }
      stc8((u64*)(h1g + ((s & 1) * 32 + g) * 16384 + pub_off), pk);
    }

    if (s <= 256) arrive_bar(cnt + s, tid);             // publish + arrive

    // ---- decoder tail (hidden under peer skew): gelu/reduce/pstg/out ----
    if (dec){
      float p0[4], p1[4];
      #pragma unroll
      for (int r = 0; r < 4; r++){
        const float dv = gelu(ad[r] + b3c);
        p0[r] = dv * w40;
        p1[r] = dv * w41;
      }
      #pragma unroll
      for (int mk = 1; mk < 16; mk <<= 1)
        #pragma unroll
        for (int r = 0; r < 4; r++){
          p0[r] += __shfl_xor(p0[r], mk);
          p1[r] += __shfl_xor(p1[r], mk);
        }
      if (m16 == 0 && q < 2){
        #pragma unroll
        for (int r = 0; r < 4; r++){
          pstg[(v * 8 + q * 4 + r) * 2 + 0] = p0[r];
          pstg[(v * 8 + q * 4 + r) * 2 + 1] = p1[r];
        }
      }
    }
    wbar();                                             // pstg visible
    if (dec && tid < 16){
      const int row = tid >> 1, o = tid & 1;
      float sum = b4o;
      #pragma unroll
      for (int w2 = 0; w2 < 8; w2++) sum += pstg[(w2 * 8 + row) * 2 + o];
      out[((size_t)(g * 64 + m * 8 + row) * 256 + (s - 2)) * 2 + o] = sum;
    }

    if (s <= 256) wait_bar(cnt + s, tid);               // h0(s+1), h1(s) ready
  }
}

extern "C" void kernel_launch(void* const* d_in, const int* in_sizes, int n_in,
                              void* d_out, int out_size, void* d_ws, size_t ws_size,
                              hipStream_t stream)
{
  const float* x    = (const float*)d_in[0];
  const float* W1   = (const float*)d_in[1];
  const float* b1   = (const float*)d_in[2];
  const float* g1   = (const float*)d_in[3];
  const float* be1  = (const float*)d_in[4];
  const float* W2   = (const float*)d_in[5];
  const float* b2   = (const float*)d_in[6];
  const float* g2   = (const float*)d_in[7];
  const float* be2  = (const float*)d_in[8];
  const float* Wih0 = (const float*)d_in[9];
  const float* Whh0 = (const float*)d_in[10];
  const float* bih0 = (const float*)d_in[11];
  const float* bhh0 = (const float*)d_in[12];
  const float* Wih1 = (const float*)d_in[13];
  const float* Whh1 = (const float*)d_in[14];
  const float* bih1 = (const float*)d_in[15];
  const float* bhh1 = (const float*)d_in[16];
  const float* W3   = (const float*)d_in[17];
  const float* b3   = (const float*)d_in[18];
  const float* W4   = (const float*)d_in[19];
  const float* b4   = (const float*)d_in[20];

  short* wsb = (short*)d_ws;

  prep_kernel<<<4232, 256, 0, stream>>>(Wih0, Whh0, Wih1, Whh1, W3, W4, wsb);
  // zero h0g + h1g + counters: bytes [2*H0G_SH, +2*(1048576*2+16640))
  hipMemsetAsync((char*)d_ws + 2168832, 0, 4227584, stream);
  curve_rec<<<256, 512, 0, stream>>>(x, W1, b1, g1, be1, W2, b2, g2, be2,
                                     bih0, bhh0, bih1, bhh1, b3, b4, W4, wsb,
                                     (float*)d_out);
}

// Round 11
// 1970.640 us; speedup vs baseline: 15.7191x; 1.0717x over previous
//
#include <hip/hip_runtime.h>
#include <math.h>

// ---------------------------------------------------------------------------
// CurvePredictor R18: R17's split-barrier schedule with the output skew
// corrected (R17 post-mortem: decoder consumed staged h1(s-1) but wrote out
// col s-1 -> col t = dec(h1(t)), one step stale, absmax 1.95e-2 ~ adjacent-
// step output delta. Also s=1 waited on cnt1(0) which nobody arrives ->
// full failsafe stall per block).
// R18 schedule, s in [0,257]:
//   [s<=256] wait cnt0(s-1); stage h0(s); accP = bs1 + h0@Bi1
//   [s<=255] acc0 = xp + h0@Bh0; G0; pointwise0 -> publish h0(s+1);
//            ARRIVE cnt0(s)                                  [mid-iter]
//   -- shadow --
//   [s>=2]   wait cnt1(s-1)   (s=1 skips: h1(0) memset-zero, writer gated)
//   [s>=1]   stage h1(s-1); [s<=256] accP += h1@Bh1; G1; pointwise1 ->
//            publish h1(s); ARRIVE cnt1(s)
//   [s>=2]   decoder MFMA on staged h1(s-1); tail -> pstg; out col s-2
// Race audit (unchanged from R17, indices shifted): h0 parity-(s&1) readers
// drain vmcnt before arrive cnt0(s); its next writer h0(s+2) is gated by
// wait cnt0(s+1)-at-iter-(s+1) -> WAR safe. h1 parity reader at iter s
// drains before arrive cnt1(s); writer h1(s+1) gated by wait cnt1(s). All
// LDS WARs barrier-separated; finite poll failsafe retained.
// Everything else identical to R16/R17 (proven): 32 groups x 8 members,
// register-resident Whh0/Wih1/Whh1/W3, relaxed agent atomics, A-packed
// u64 publication, rcp transcendentals, 136.5KB LDS -> 1 block/CU.
// ---------------------------------------------------------------------------

typedef short s8v __attribute__((ext_vector_type(8)));   // 8 x bf16
typedef float f4v __attribute__((ext_vector_type(4)));   // 4 x f32
typedef unsigned long long u64;

// ws layout (units: shorts)
#define IMG_SH   1084416                 // swizzled weight image
#define H0G_SH   (IMG_SH)                // h0g[2 par][32 g][32 tiles][512]
#define H1G_SH   (H0G_SH + 1048576)
#define CNT_SH   (H1G_SH + 1048576)      // u32 cnt[2][32][260] = 33280 shorts
#define ENC_SH   (CNT_SH + 33280)        // encg[32 g][32 tiles][512]

__device__ __forceinline__ f4v mfma16(s8v a, s8v b, f4v c){
  return __builtin_amdgcn_mfma_f32_16x16x32_bf16(a, b, c, 0, 0, 0);
}
__device__ __forceinline__ short f2bf(float f){
  unsigned u = __float_as_uint(f);
  u = u + 0x7FFFu + ((u >> 16) & 1u);
  return (short)(u >> 16);
}
__device__ __forceinline__ float wred(float v){
  #pragma unroll
  for (int o = 32; o; o >>= 1) v += __shfl_xor(v, o);
  return v;
}
__device__ __forceinline__ float rcpf(float x){ return __builtin_amdgcn_rcpf(x); }
__device__ __forceinline__ float sigm(float x){ return rcpf(1.0f + __expf(-x)); }
__device__ __forceinline__ float tnh(float x){
  x = fminf(15.0f, fmaxf(-15.0f, x));
  float e = __expf(2.0f * x);
  return (e - 1.0f) * rcpf(e + 1.0f);
}
__device__ __forceinline__ float gelu(float v){
  return 0.5f * v * (1.0f + erff(v * 0.70710678118654752440f));
}

// ---- coherent (agent/IC-level) access, compiler-modeled ----
__device__ __forceinline__ u64 ldc8(const u64* p){
  return __hip_atomic_load(p, __ATOMIC_RELAXED, __HIP_MEMORY_SCOPE_AGENT);
}
__device__ __forceinline__ void stc2(short* p, short v){
  __hip_atomic_store(p, v, __ATOMIC_RELAXED, __HIP_MEMORY_SCOPE_AGENT);
}
__device__ __forceinline__ void stc8(u64* p, u64 v){
  __hip_atomic_store(p, v, __ATOMIC_RELAXED, __HIP_MEMORY_SCOPE_AGENT);
}
__device__ __forceinline__ void wbar(){                 // lgkm-only raw barrier
  asm volatile("s_waitcnt lgkmcnt(0)" ::: "memory");
  __builtin_amdgcn_s_barrier();
}
// arrive: all waves' global stores drained, then one agent-relaxed add
__device__ __forceinline__ void arrive_bar(unsigned* c, int tid){
  asm volatile("s_waitcnt vmcnt(0) lgkmcnt(0)" ::: "memory");
  __builtin_amdgcn_s_barrier();
  if (tid == 0)
    __hip_atomic_fetch_add(c, 1u, __ATOMIC_RELAXED, __HIP_MEMORY_SCOPE_AGENT);
}
// wait: poll to 8 members, then release the block
__device__ __forceinline__ void wait_bar(unsigned* c, int tid){
  if (tid == 0){
    unsigned it = 0;
    while (__hip_atomic_load(c, __ATOMIC_RELAXED, __HIP_MEMORY_SCOPE_AGENT) < 8u
           && ++it < (1u << 18))
      __builtin_amdgcn_s_sleep(2);        // failsafe: finite on bug
  }
  __builtin_amdgcn_s_barrier();
  asm volatile("" ::: "memory");          // no hoisting of post-barrier loads
}

// weight image: identical swizzle to R5-R17 (interior lane-linear lane*8):
// mats (1024x256): s*16384 + g*4096 + kk*512 + lane*8 + j ; lane=q*16+m16,
// col=s*16+m16, k=kk*32+q*8+j, gate-row=g*256+col.
// [0,262144) Wih0 [262144,524288) Whh0 [524288,786432) Wih1 [786432,1048576) Whh1
// W3 [128][256]: 1048576 + s2*4096 + kk*512 + lane*8
__global__ void prep_kernel(
    const float* __restrict__ Wih0, const float* __restrict__ Whh0,
    const float* __restrict__ Wih1, const float* __restrict__ Whh1,
    const float* __restrict__ W3,   const float* __restrict__ W4,
    short* __restrict__ wsb)
{
  const int i = blockIdx.x * 256 + threadIdx.x;
  if (i >= 1083392) return;
  float v;
  if (i < 1048576){
    const int seg = i >> 18;
    const int r   = i & 262143;
    const int s   = r >> 14;
    const int g   = (r >> 12) & 3;
    const int kk  = (r >> 9) & 7;
    const int q   = (r >> 7) & 3;
    const int m16 = (r >> 3) & 15;
    const int j   = r & 7;
    const int hid = s * 16 + m16;
    const int k   = kk * 32 + q * 8 + j;
    const float* mt = (seg == 0) ? Wih0 : (seg == 1) ? Whh0 : (seg == 2) ? Wih1 : Whh1;
    v = mt[(g * 256 + hid) * 256 + k];
  } else if (i < 1081344){
    const int r   = i - 1048576;
    const int s2  = r >> 12;
    const int kk  = (r >> 9) & 7;
    const int q   = (r >> 7) & 3;
    const int m16 = (r >> 3) & 15;
    const int j   = r & 7;
    v = W3[(s2 * 16 + m16) * 256 + kk * 32 + q * 8 + j];
  } else {
    const int r   = i - 1081344;
    const int kk  = (r >> 9) & 3;
    const int q   = (r >> 7) & 3;
    const int m16 = (r >> 3) & 15;
    const int j   = r & 7;
    const int k   = kk * 32 + q * 8 + j;
    v = (m16 < 2) ? W4[m16 * 128 + k] : 0.0f;
  }
  wsb[i] = f2bf(v);
}

// h/enc buffers are A-packed (64 rows x 256 cols -> 32 tiles x 512 shorts):
//   tile = (row>>4)*8 + (col>>5); interior = (((col>>3)&3)*16 + (row&15))*8 + (col&7)
// gemm lane (q,m16) reads tile (rt*8+kk) at interior lane*8 (contiguous).
// Pointwise thread tid owns exactly u64 index (tid&127) of tile (tid>>7)*8+m,
// so publication is one stc8 per thread per layer (proven R15-R16).

__global__ __launch_bounds__(512) void curve_rec(
    const float* __restrict__ x,
    const float* __restrict__ W1, const float* __restrict__ b1,
    const float* __restrict__ g1, const float* __restrict__ be1,
    const float* __restrict__ W2, const float* __restrict__ b2,
    const float* __restrict__ g2, const float* __restrict__ be2,
    const float* __restrict__ bih0, const float* __restrict__ bhh0,
    const float* __restrict__ bih1, const float* __restrict__ bhh1,
    const float* __restrict__ b3, const float* __restrict__ b4,
    const float* __restrict__ W4,
    short* __restrict__ wsb,
    float* __restrict__ out)
{
  const int tid  = threadIdx.x;
  const int v    = tid >> 6;          // wave 0..7
  const int lane = tid & 63;
  const int q    = lane >> 4;
  const int m16  = lane & 15;
  const int bid  = blockIdx.x;
  const int g    = bid & 31;          // group (64 batch rows)
  const int m    = bid >> 5;          // member (32 hidden cols)
  const int gate = v & 3;
  const int ch   = v >> 2;            // col-half of the member's 32-col slice

  const short* img = wsb;
  short* h0g  = wsb + H0G_SH;
  short* h1g  = wsb + H1G_SH;
  short* encg = wsb + ENC_SH;
  unsigned* cntb = (unsigned*)(wsb + CNT_SH);
  unsigned* cnt0 = cntb + g * 260;
  unsigned* cnt1 = cntb + 32 * 260 + g * 260;

  __shared__ __align__(16) short ldsH0[16384];     // 32KB: h0 stage
  __shared__ __align__(16) short ldsX [16384];     // 32KB: h1 stage
  __shared__ __align__(16) float Gst[2][256 * 36]; // 72KB: gate exchange
  __shared__ __align__(16) float pstg[128];        // 136.5KB -> 1 blk/CU

  // ---- persistent register-resident weight fragments (loaded once) ----
  s8v Bh0[8], Bi1[8], Bh1[8], W3r[8];
  const int sIdx = 2 * m + ch;        // 16-col image slice index
  #pragma unroll
  for (int kk = 0; kk < 8; kk++){
    const int off = sIdx * 16384 + gate * 4096 + kk * 512 + (lane << 3);
    Bh0[kk] = *(const s8v*)(img + 262144 + off);
    Bi1[kk] = *(const s8v*)(img + 524288 + off);
    Bh1[kk] = *(const s8v*)(img + 786432 + off);
    W3r[kk] = *(const s8v*)(img + 1048576 + v * 4096 + kk * 512 + (lane << 3));
  }
  const float b3c = b3[v * 16 + m16];
  const float w40 = W4[v * 16 + m16];
  const float w41 = W4[128 + v * 16 + m16];
  const float b4o = b4[tid & 1];
  const int   n0  = gate * 256 + m * 32 + ch * 16 + m16;
  const float bs1v = bih1[n0] + bhh1[n0];
  // decoder A constants (rows m*8 + m16-window; rows>=8 feed discarded lanes)
  const int row3 = m * 8 + m16, rt3 = row3 >> 4, rin3 = row3 & 15;
  // pointwise ownership: thread tid -> 4 cells = one u64 of the A-packed slice
  const int rt_p = tid >> 7, rem = tid & 127;
  const int cq_p = (rem >> 5) & 3, r16p = (rem >> 1) & 15, c4h = rem & 1;
  const int rowp  = rt_p * 16 + r16p;            // row within group (0..63)
  const int coltp = cq_p * 8 + c4h * 4;          // col within member slice
  const int pub_off = (rt_p * 8 + m) * 512 + rem * 4;   // shorts in layer chunk

  // ---- encoder: wave v computes batch row m*8+v of this group ----
  {
    const int row_l = m * 8 + v;
    const int r = g * 64 + row_l;
    float xv[5];
    #pragma unroll
    for (int k = 0; k < 5; k++) xv[k] = x[r * 5 + k];
    float a0 = b1[lane], a1 = b1[lane + 64];
    #pragma unroll
    for (int k = 0; k < 5; k++){
      a0 += xv[k] * W1[lane * 5 + k];
      a1 += xv[k] * W1[(lane + 64) * 5 + k];
    }
    a0 = gelu(a0); a1 = gelu(a1);
    float mean = wred(a0 + a1) * (1.0f / 128.0f);
    float d0 = a0 - mean, d1 = a1 - mean;
    float inv = rsqrtf(wred(d0 * d0 + d1 * d1) * (1.0f / 128.0f) + 1e-5f);
    float y0 = d0 * inv * g1[lane]      + be1[lane];
    float y1 = d1 * inv * g1[lane + 64] + be1[lane + 64];

    float acc2[4];
    #pragma unroll
    for (int uu = 0; uu < 4; uu++) acc2[uu] = b2[lane + 64 * uu];
    for (int k = 0; k < 64; k++){
      float v0 = __shfl(y0, k);
      float v1 = __shfl(y1, k);
      #pragma unroll
      for (int uu = 0; uu < 4; uu++){
        const float* wr = W2 + (lane + 64 * uu) * 128;
        acc2[uu] += v0 * wr[k] + v1 * wr[k + 64];
      }
    }
    #pragma unroll
    for (int uu = 0; uu < 4; uu++) acc2[uu] = gelu(acc2[uu]);
    float s = acc2[0] + acc2[1] + acc2[2] + acc2[3];
    mean = wred(s) * (1.0f / 256.0f);
    float vv = 0.0f;
    #pragma unroll
    for (int uu = 0; uu < 4; uu++){ float d = acc2[uu] - mean; vv += d * d; }
    inv = rsqrtf(wred(vv) * (1.0f / 256.0f) + 1e-5f);
    short* eb = encg + g * 16384;
    const int rt_e = row_l >> 4, rin_e = row_l & 15;
    const int qe = (lane >> 3) & 3, je = lane & 7;
    #pragma unroll
    for (int uu = 0; uu < 4; uu++){
      const int c = lane + 64 * uu;
      const float e = (acc2[uu] - mean) * inv * g2[c] + be2[c];
      stc2(eb + (rt_e * 8 + (c >> 5)) * 512 + (qe * 16 + rin_e) * 8 + je, f2bf(e));
    }
  }
  arrive_bar(cnt0 + 258, tid);
  wait_bar(cnt0 + 258, tid);                   // enc visible group-wide

  // ---- stage enc -> ldsH0; xp = enc @ Wih0_slice + (bih0+bhh0) ----
  {
    const u64* src = (const u64*)(encg + g * 16384);
    u64 t[8];
    #pragma unroll
    for (int u = 0; u < 8; u++) t[u] = ldc8(src + tid + u * 512);
    #pragma unroll
    for (int u = 0; u < 8; u++) ((u64*)ldsH0)[tid + u * 512] = t[u];
  }
  wbar();
  f4v xp[4];
  {
    s8v Wi0[8];
    #pragma unroll
    for (int kk = 0; kk < 8; kk++)
      Wi0[kk] = *(const s8v*)(img + sIdx * 16384 + gate * 4096 + kk * 512 + (lane << 3));
    const float bi = bih0[n0] + bhh0[n0];
    #pragma unroll
    for (int rt = 0; rt < 4; rt++){ f4v t = {bi, bi, bi, bi}; xp[rt] = t; }
    const short* A0 = ldsH0 + (lane << 3);
    #pragma unroll
    for (int rt = 0; rt < 4; rt++)
      #pragma unroll
      for (int kk = 0; kk < 8; kk++)
        xp[rt] = mfma16(*(const s8v*)(A0 + (rt * 8 + kk) * 512), Wi0[kk], xp[rt]);
  }
  wbar();                                      // ldsH0 free for s=0 stage

  float c0[4] = {0.f,0.f,0.f,0.f}, c1[4] = {0.f,0.f,0.f,0.f};

  // ------------------ split-barrier recurrence: iter s in [0,257] ----------
  // critical: h0(s+1)=f(h0(s)) publish + arrive cnt0(s)       [s<=255]
  // shadow:   h1(s)=f(h0(s),h1(s-1)) publish + arrive cnt1(s) [1<=s<=256]
  //           decoder(staged h1(s-1)) -> out col s-2          [s>=2]
  #pragma unroll 1
  for (int s = 0; s <= 257; s++){
    const bool stg0 = (s <= 256);    // stage h0(s) (h1(256) needs h0(256))
    const bool g0c  = (s <= 255);    // acc0 + publish h0(s+1)
    const bool gPc  = (s <= 256);    // accP = bs1 + h0@Bi1
    const bool stg1 = (s >= 1);      // stage h1(s-1)
    const bool g1c  = (s >= 1 && s <= 256);  // accP += h1@Bh1, publish h1(s)
    const bool decM = (s >= 2);      // decoder on staged h1(s-1), out col s-2

    // ---- critical: wait h0(s), stage, gemm, G0, pointwise0, publish ----
    if (s >= 1 && stg0) wait_bar(cnt0 + (s - 1), tid);
    if (stg0){
      const u64* h0src = (const u64*)(h0g + ((s & 1) * 32 + g) * 16384);
      u64 t0[8];
      #pragma unroll
      for (int u = 0; u < 8; u++) t0[u] = ldc8(h0src + tid + u * 512);
      #pragma unroll
      for (int u = 0; u < 8; u++) ((u64*)ldsH0)[tid + u * 512] = t0[u];
    }
    wbar();                                           // (1) h0 staged

    f4v acc0[4], accP[4];
    if (stg0){
      #pragma unroll
      for (int rt = 0; rt < 4; rt++){
        acc0[rt] = xp[rt];
        f4v t = {bs1v, bs1v, bs1v, bs1v};
        accP[rt] = t;
      }
      const short* A0 = ldsH0 + (lane << 3);
      if (g0c){
        #pragma unroll
        for (int rt = 0; rt < 4; rt++)
          #pragma unroll
          for (int kk = 0; kk < 8; kk++){
            const s8v a = *(const s8v*)(A0 + (rt * 8 + kk) * 512);
            acc0[rt] = mfma16(a, Bh0[kk], acc0[rt]);
            accP[rt] = mfma16(a, Bi1[kk], accP[rt]);
          }
      } else if (gPc){
        #pragma unroll
        for (int rt = 0; rt < 4; rt++)
          #pragma unroll
          for (int kk = 0; kk < 8; kk++)
            accP[rt] = mfma16(*(const s8v*)(A0 + (rt * 8 + kk) * 512), Bi1[kk], accP[rt]);
      }
    }
    if (g0c){
      #pragma unroll
      for (int rt = 0; rt < 4; rt++)
        #pragma unroll
        for (int r = 0; r < 4; r++)
          Gst[0][(gate * 64 + rt * 16 + q * 4 + r) * 36 + ch * 16 + m16] = acc0[rt][r];
    }
    wbar();                                           // (2) G0 visible
    if (g0c){
      const float* G0 = &Gst[0][0];
      const f4v gi = *(const f4v*)&G0[(0 * 64 + rowp) * 36 + coltp];
      const f4v gf = *(const f4v*)&G0[(1 * 64 + rowp) * 36 + coltp];
      const f4v gg = *(const f4v*)&G0[(2 * 64 + rowp) * 36 + coltp];
      const f4v go = *(const f4v*)&G0[(3 * 64 + rowp) * 36 + coltp];
      u64 pk = 0;
      #pragma unroll
      for (int j = 0; j < 4; j++){
        const float ii = sigm(gi[j]), ff = sigm(gf[j]);
        const float ga = tnh(gg[j]),  oo = sigm(go[j]);
        c0[j] = ff * c0[j] + ii * ga;
        pk |= (u64)(unsigned short)f2bf(oo * tnh(c0[j])) << (16 * j);
      }
      stc8((u64*)(h0g + ((((s + 1) & 1)) * 32 + g) * 16384 + pub_off), pk);
      arrive_bar(cnt0 + s, tid);                      // MID-ITER arrive
    }

    // ---- shadow: wait h1(s-1) (near-instant), stage, finish layer 1 ----
    if (s >= 2 && stg1) wait_bar(cnt1 + (s - 1), tid);  // s=1: h1(0) pre-zeroed
    if (stg1){
      const u64* h1src = (const u64*)(h1g + ((((s + 1) & 1)) * 32 + g) * 16384);
      u64 t1[8];
      #pragma unroll
      for (int u = 0; u < 8; u++) t1[u] = ldc8(h1src + tid + u * 512);
      #pragma unroll
      for (int u = 0; u < 8; u++) ((u64*)ldsX)[tid + u * 512] = t1[u];
    }
    wbar();                                           // (3) h1 staged

    if (g1c){
      const short* A1 = ldsX + (lane << 3);
      #pragma unroll
      for (int rt = 0; rt < 4; rt++)
        #pragma unroll
        for (int kk = 0; kk < 8; kk++)
          accP[rt] = mfma16(*(const s8v*)(A1 + (rt * 8 + kk) * 512), Bh1[kk], accP[rt]);
    }
    f4v ad = {0.f, 0.f, 0.f, 0.f};
    if (decM){
      #pragma unroll
      for (int kk = 0; kk < 8; kk++){
        const s8v a3 = *(const s8v*)(ldsX + (rt3 * 8 + kk) * 512 + (q * 16 + rin3) * 8);
        ad = mfma16(a3, W3r[kk], ad);
      }
    }
    if (g1c){
      #pragma unroll
      for (int rt = 0; rt < 4; rt++)
        #pragma unroll
        for (int r = 0; r < 4; r++)
          Gst[1][(gate * 64 + rt * 16 + q * 4 + r) * 36 + ch * 16 + m16] = accP[rt][r];
    }
    wbar();                                           // (4) G1 visible

    if (g1c){
      const float* G1 = &Gst[1][0];
      const f4v gi = *(const f4v*)&G1[(0 * 64 + rowp) * 36 + coltp];
      const f4v gf = *(const f4v*)&G1[(1 * 64 + rowp) * 36 + coltp];
      const f4v gg = *(const f4v*)&G1[(2 * 64 + rowp) * 36 + coltp];
      const f4v go = *(const f4v*)&G1[(3 * 64 + rowp) * 36 + coltp];
      u64 pk = 0;
      #pragma unroll
      for (int j = 0; j < 4; j++){
        const float ii = sigm(gi[j]), ff = sigm(gf[j]);
        const float ga = tnh(gg[j]),  oo = sigm(go[j]);
        c1[j] = ff * c1[j] + ii * ga;
        pk |= (u64)(unsigned short)f2bf(oo * tnh(c1[j])) << (16 * j);
      }
      stc8((u64*)(h1g + ((s & 1) * 32 + g) * 16384 + pub_off), pk);
    }
    if (decM){
      float p0[4], p1[4];
      #pragma unroll
      for (int r = 0; r < 4; r++){
        const float dv = gelu(ad[r] + b3c);
        p0[r] = dv * w40;
        p1[r] = dv * w41;
      }
      #pragma unroll
      for (int mk = 1; mk < 16; mk <<= 1)
        #pragma unroll
        for (int r = 0; r < 4; r++){
          p0[r] += __shfl_xor(p0[r], mk);
          p1[r] += __shfl_xor(p1[r], mk);
        }
      if (m16 == 0 && q < 2){
        #pragma unroll
        for (int r = 0; r < 4; r++){
          pstg[(v * 8 + q * 4 + r) * 2 + 0] = p0[r];
          pstg[(v * 8 + q * 4 + r) * 2 + 1] = p1[r];
        }
      }
    }
    if (g1c) arrive_bar(cnt1 + s, tid);               // END-ITER arrive
    else     wbar();                                  // pstg visibility (s=0,257)
    if (decM && tid < 16){
      const int row = tid >> 1, o = tid & 1;
      float sum = b4o;
      #pragma unroll
      for (int w2 = 0; w2 < 8; w2++) sum += pstg[(w2 * 8 + row) * 2 + o];
      out[((size_t)(g * 64 + m * 8 + row) * 256 + (s - 2)) * 2 + o] = sum;
    }
  }
}

extern "C" void kernel_launch(void* const* d_in, const int* in_sizes, int n_in,
                              void* d_out, int out_size, void* d_ws, size_t ws_size,
                              hipStream_t stream)
{
  const float* x    = (const float*)d_in[0];
  const float* W1   = (const float*)d_in[1];
  const float* b1   = (const float*)d_in[2];
  const float* g1   = (const float*)d_in[3];
  const float* be1  = (const float*)d_in[4];
  const float* W2   = (const float*)d_in[5];
  const float* b2   = (const float*)d_in[6];
  const float* g2   = (const float*)d_in[7];
  const float* be2  = (const float*)d_in[8];
  const float* Wih0 = (const float*)d_in[9];
  const float* Whh0 = (const float*)d_in[10];
  const float* bih0 = (const float*)d_in[11];
  const float* bhh0 = (const float*)d_in[12];
  const float* Wih1 = (const float*)d_in[13];
  const float* Whh1 = (const float*)d_in[14];
  const float* bih1 = (const float*)d_in[15];
  const float* bhh1 = (const float*)d_in[16];
  const float* W3   = (const float*)d_in[17];
  const float* b3   = (const float*)d_in[18];
  const float* W4   = (const float*)d_in[19];
  const float* b4   = (const float*)d_in[20];

  short* wsb = (short*)d_ws;

  prep_kernel<<<4232, 256, 0, stream>>>(Wih0, Whh0, Wih1, Whh1, W3, W4, wsb);
  // zero h0g + h1g + counters: bytes [2*H0G_SH, +2*(1048576*2 + 33280))
  hipMemsetAsync((char*)d_ws + 2168832, 0, 4260864, stream);
  curve_rec<<<256, 512, 0, stream>>>(x, W1, b1, g1, be1, W2, b2, g2, be2,
                                     bih0, bhh0, bih1, bhh1, b3, b4, W4, wsb,
                                     (float*)d_out);
}